// Round 13
// baseline (322.917 us; speedup 1.0000x reference)
//
#include <hip/hip_runtime.h>

#define D 128
#define BUNROLL 8
#define RPB 64                  // rows per bucket
#define CAP 1536                // max edges sorted in LDS per bucket (avg ~960, sigma~31)
#define MAXK 4096               // max buckets (LDS histogram size)
#define CHUNK4 16384            // edges per block in hist4/scatter4 (identical mapping!)
#define STILE 1024              // scan tile

__device__ __forceinline__ unsigned f2bf_rne(float x) {
    unsigned u = __float_as_uint(x);
    return (u + 0x7fffu + ((u >> 16) & 1u)) >> 16;
}

// ---------------- relation transform -> bf16 table (fast path) ----------------
__global__ void transform2_bf_kernel(const float* __restrict__ Rin, const float* __restrict__ Win,
                                     const float* __restrict__ Rout, const float* __restrict__ Wout,
                                     unsigned short* __restrict__ T_bf, int nrel) {
    __shared__ float row[D];
    int b = blockIdx.x;
    bool second = (b >= nrel);
    const float* R = second ? Rout : Rin;
    const float* W = second ? Wout : Win;
    int r = second ? b - nrel : b;
    int t = threadIdx.x;
    row[t] = R[r * D + t];
    __syncthreads();
    float acc = 0.f;
#pragma unroll 8
    for (int k = 0; k < D; ++k) acc += row[k] * W[k * D + t];
    T_bf[(size_t)b * D + t] = (unsigned short)f2bf_rne(acc);
}

// f32 version (fallback path)
__global__ void transform2_kernel(const float* __restrict__ Rin, const float* __restrict__ Win,
                                  const float* __restrict__ Rout, const float* __restrict__ Wout,
                                  float* __restrict__ T_all, int nrel) {
    __shared__ float row[D];
    int b = blockIdx.x;
    bool second = (b >= nrel);
    const float* R = second ? Rout : Rin;
    const float* W = second ? Wout : Win;
    int r = second ? b - nrel : b;
    int t = threadIdx.x;
    row[t] = R[r * D + t];
    __syncthreads();
    float acc = 0.f;
#pragma unroll 8
    for (int k = 0; k < D; ++k) acc += row[k] * W[k * D + t];
    T_all[(size_t)b * D + t] = acc;
}

// ---------------- pass 1: per-block LDS bucket histogram (NO global atomics) ----------------
__global__ __launch_bounds__(512) void hist4_kernel(
        const int* __restrict__ rows, int E2,
        unsigned* __restrict__ cnt, int NB, int K) {
    __shared__ unsigned h[MAXK];
    int tid = threadIdx.x, blk = blockIdx.x;
    for (int i = tid; i < K; i += 512) h[i] = 0;
    __syncthreads();
    long s = (long)blk * CHUNK4;
    long e = s + CHUNK4; if (e > E2) e = E2;
    for (long i = s + tid; i < e; i += 512)
        atomicAdd(&h[((unsigned)rows[i]) >> 6], 1u);
    __syncthreads();
    for (int i = tid; i < K; i += 512)
        cnt[(size_t)i * NB + blk] = h[i];
}

// ---------------- device-wide scan over n=NB*K counters ----------------
__global__ __launch_bounds__(256) void tile_sum_u32(const unsigned int* __restrict__ cnt,
                                                    unsigned int* __restrict__ tsum, int n) {
    int tid = threadIdx.x;
    int i0 = blockIdx.x * STILE + tid * 4;
    unsigned int s = 0;
#pragma unroll
    for (int k = 0; k < 4; ++k) {
        int i = i0 + k;
        if (i < n) s += cnt[i];
    }
    __shared__ unsigned int ls[256];
    ls[tid] = s;
    __syncthreads();
    for (int off = 128; off >= 1; off >>= 1) {
        if (tid < off) ls[tid] += ls[tid + off];
        __syncthreads();
    }
    if (tid == 0) tsum[blockIdx.x] = ls[0];
}

__global__ void scan_tiles_kernel(const unsigned int* __restrict__ tile_sums,
                                  unsigned int* __restrict__ tile_off,
                                  unsigned int* __restrict__ base, int ntiles, int n) {
    int t = threadIdx.x; // blockDim = 1024
    __shared__ unsigned int ls[1024];
    unsigned int v = (t < ntiles) ? tile_sums[t] : 0u;
    ls[t] = v;
    __syncthreads();
    for (int off = 1; off < 1024; off <<= 1) {
        unsigned int add = (t >= off) ? ls[t - off] : 0u;
        __syncthreads();
        ls[t] += add;
        __syncthreads();
    }
    if (t < ntiles) tile_off[t] = ls[t] - v; // exclusive
    if (t == 1023) base[n] = ls[1023];       // grand total
}

// in-place safe when base==cnt
__global__ __launch_bounds__(256) void base_write_u32(const unsigned int* __restrict__ cnt,
                                                      const unsigned int* __restrict__ tile_off,
                                                      unsigned int* __restrict__ base, int n) {
    int tid = threadIdx.x;
    int i0 = blockIdx.x * STILE + tid * 4;
    unsigned int c[4];
#pragma unroll
    for (int k = 0; k < 4; ++k) {
        int i = i0 + k;
        c[k] = (i < n) ? cnt[i] : 0u;
    }
    unsigned int s = c[0] + c[1] + c[2] + c[3];
    __shared__ unsigned int ls[256];
    ls[tid] = s;
    __syncthreads();
    for (int off = 1; off < 256; off <<= 1) {
        unsigned int add = (tid >= off) ? ls[tid - off] : 0u;
        __syncthreads();
        ls[tid] += add;
        __syncthreads();
    }
    unsigned int run = (tid > 0 ? ls[tid - 1] : 0u) + tile_off[blockIdx.x];
#pragma unroll
    for (int k = 0; k < 4; ++k) {
        int i = i0 + k;
        if (i < n) base[i] = run;
        run += c[k];
    }
}

// ---------------- pass 2: scatter with LDS ranks (NO global atomics) ----------------
// payload = (col, (row&63)<<10 | type)
__global__ __launch_bounds__(512) void scatter4_kernel(
        const int* __restrict__ rows, const int* __restrict__ cols,
        const int* __restrict__ etype, const unsigned* __restrict__ base,
        uint2* __restrict__ payload, int E, int E2, int nrel, int NB, int K) {
    __shared__ unsigned cur[MAXK];
    int tid = threadIdx.x, blk = blockIdx.x;
    for (int i = tid; i < K; i += 512) cur[i] = base[(size_t)i * NB + blk];
    __syncthreads();
    long s = (long)blk * CHUNK4;
    long e = s + CHUNK4; if (e > E2) e = E2;
    for (long i = s + tid; i < e; i += 512) {
        unsigned r = (unsigned)rows[i];
        unsigned c = (unsigned)cols[i];
        unsigned t = (unsigned)etype[i];
        unsigned ty = t + ((i < E) ? 0u : (unsigned)nrel);
        unsigned pos = atomicAdd(&cur[r >> 6], 1u);   // LDS atomic
        payload[pos] = make_uint2(c, ((r & 63u) << 10) | ty);
    }
}

// ---------------- degrees + per-bucket row offsets from sorted payload ----------------
__global__ __launch_bounds__(512) void degsort_kernel(
        const unsigned* __restrict__ base, const uint2* __restrict__ payload,
        float* __restrict__ dinvAll, unsigned* __restrict__ rowBase,
        int nent, int nrel, int NB, int K) {
    __shared__ unsigned h2[RPB * 2];
    __shared__ unsigned sc[RPB];
    int tid = threadIdx.x, b = blockIdx.x;
    if (tid < RPB * 2) h2[tid] = 0;
    __syncthreads();
    size_t NBK = (size_t)NB * K;
    unsigned s = base[(size_t)b * NB];
    unsigned e = (b + 1 < K) ? base[(size_t)(b + 1) * NB] : base[NBK];
    for (unsigned i = s + tid; i < e; i += 512) {
        unsigned y = payload[i].y;
        unsigned lr = (y >> 10) & 63u;
        unsigned fo = ((y & 1023u) >= (unsigned)nrel) ? 1u : 0u;
        atomicAdd(&h2[lr * 2 + fo], 1u);
    }
    __syncthreads();
    unsigned tot = 0;
    if (tid < RPB) { tot = h2[tid * 2] + h2[tid * 2 + 1]; sc[tid] = tot; }
    __syncthreads();
    for (int off = 1; off < RPB; off <<= 1) {
        unsigned v = 0;
        if (tid < RPB && tid >= off) v = sc[tid - off];
        __syncthreads();
        if (tid < RPB) sc[tid] += v;
        __syncthreads();
    }
    if (tid < RPB) {
        rowBase[(size_t)b * RPB + tid] = sc[tid] - tot;   // exclusive prefix
        int row = (b << 6) + tid;
        if (row < nent) {
            unsigned a = h2[tid * 2], o = h2[tid * 2 + 1];
            dinvAll[row]        = a ? rsqrtf((float)a) : 0.f;
            dinvAll[nent + row] = o ? rsqrtf((float)o) : 0.f;
        }
    }
}

// unpack-and-FMA: 8 bf16 elems of t scaled by c into a[0..7]
#define UNPACK_FMA(a, c, t)                                         \
    a[0] += (c) * __uint_as_float((t).x << 16);                     \
    a[1] += (c) * __uint_as_float((t).x & 0xffff0000u);             \
    a[2] += (c) * __uint_as_float((t).y << 16);                     \
    a[3] += (c) * __uint_as_float((t).y & 0xffff0000u);             \
    a[4] += (c) * __uint_as_float((t).z << 16);                     \
    a[5] += (c) * __uint_as_float((t).z & 0xffff0000u);             \
    a[6] += (c) * __uint_as_float((t).w << 16);                     \
    a[7] += (c) * __uint_as_float((t).w & 0xffff0000u);

// ---------------- per-bucket reorder (coeff at staging) + uint4 accumulate + BN stats ----------------
__global__ __launch_bounds__(512) void accum4_kernel(
        const unsigned* __restrict__ base, const uint2* __restrict__ payload,
        const unsigned short* __restrict__ T_bf, const float* __restrict__ dinvAll,
        const unsigned* __restrict__ rowBase,
        float* __restrict__ out, float* __restrict__ sums, float* __restrict__ sumsq,
        int nent, int nrel, int NB, int K) {
    __shared__ uint2 sp[CAP];              // 12 KB: (coeff_bits, lr<<10|ty)
    __shared__ unsigned hstart[RPB];
    __shared__ unsigned hcur[RPB];
    __shared__ float ls[D], lq[D];
    int tid = threadIdx.x;
    int b = blockIdx.x;
    size_t NBK = (size_t)NB * K;
    unsigned start = base[(size_t)b * NB];
    unsigned end   = (b + 1 < K) ? base[(size_t)(b + 1) * NB] : base[NBK];
    int n = (int)(end - start);
    int nin = n < CAP ? n : CAP;
    int row0 = b << 6;
    unsigned unrel = (unsigned)nrel;

    if (tid < D) { ls[tid] = 0.f; lq[tid] = 0.f; }

    if (n <= CAP) {
        if (tid < RPB) {
            unsigned v = rowBase[(size_t)b * RPB + tid];
            hstart[tid] = v;
            hcur[tid] = v;
        }
        __syncthreads();
        for (int i = tid; i < nin; i += 512) {
            uint2 p = payload[start + i];
            unsigned lr = (p.y >> 10) & 63u;
            unsigned ty = p.y & 1023u;
            int off = (ty < unrel) ? 0 : nent;
            float c = 0.5f * dinvAll[off + row0 + (int)lr] * dinvAll[off + p.x];
            unsigned pos = atomicAdd(&hcur[lr], 1u);
            sp[pos] = make_uint2(__float_as_uint(c), p.y);
        }
        __syncthreads();
    } else {
        if (tid < RPB) hstart[tid] = 0;
        __syncthreads();
        for (int i = tid; i < nin; i += 512)
            atomicAdd(&hstart[(payload[start + i].y >> 10) & 63u], 1u);
        __syncthreads();
        for (int off = 1; off < RPB; off <<= 1) {
            unsigned v = 0;
            if (tid < RPB && tid >= off) v = hstart[tid - off];
            __syncthreads();
            if (tid < RPB) hstart[tid] += v;
            __syncthreads();
        }
        unsigned ex = 0;
        if (tid < RPB) ex = tid ? hstart[tid - 1] : 0u;
        __syncthreads();
        if (tid < RPB) { hstart[tid] = ex; hcur[tid] = ex; }
        __syncthreads();
        for (int i = tid; i < nin; i += 512) {
            uint2 p = payload[start + i];
            unsigned lr = (p.y >> 10) & 63u;
            unsigned ty = p.y & 1023u;
            int off = (ty < unrel) ? 0 : nent;
            float c = 0.5f * dinvAll[off + row0 + (int)lr] * dinvAll[off + p.x];
            unsigned pos = atomicAdd(&hcur[lr], 1u);
            sp[pos] = make_uint2(__float_as_uint(c), p.y);
        }
        __syncthreads();
    }

    const uint4* T4u = (const uint4*)T_bf;   // one row = 128 bf16 = 16 uint4
    float4* out4 = (float4*)out;
    int hw = tid >> 5, l32 = tid & 31;       // 16 groups of 32 lanes
    int l16 = l32 & 15;
    int half = l32 >> 4;                     // 0: even edges, 1: odd edges
    float sacc[8], qacc[8];
#pragma unroll
    for (int j = 0; j < 8; ++j) { sacc[j] = 0.f; qacc[j] = 0.f; }

    for (int rr = 0; rr < RPB / 16; ++rr) {  // 4 rows per group
        int r = (hw << 2) + rr;
        int row = row0 + r;
        unsigned s0 = hstart[r];
        unsigned s1 = (r < RPB - 1) ? hstart[r + 1] : (unsigned)nin;
        float a[8];
#pragma unroll
        for (int j = 0; j < 8; ++j) a[j] = 0.f;
        unsigned i = s0 + half;
        for (; i + 6 < s1; i += 8) {       // 4 chains per lane, 8 edges per group
            uint2 p0 = sp[i], p1 = sp[i + 2], p2 = sp[i + 4], p3 = sp[i + 6];
            uint4 t0 = T4u[(size_t)(p0.y & 1023u) * 16 + l16];
            uint4 t1 = T4u[(size_t)(p1.y & 1023u) * 16 + l16];
            uint4 t2 = T4u[(size_t)(p2.y & 1023u) * 16 + l16];
            uint4 t3 = T4u[(size_t)(p3.y & 1023u) * 16 + l16];
            float c0 = __uint_as_float(p0.x), c1 = __uint_as_float(p1.x);
            float c2 = __uint_as_float(p2.x), c3 = __uint_as_float(p3.x);
            UNPACK_FMA(a, c0, t0)
            UNPACK_FMA(a, c1, t1)
            UNPACK_FMA(a, c2, t2)
            UNPACK_FMA(a, c3, t3)
        }
        for (; i < s1; i += 2) {
            uint2 p = sp[i];
            uint4 t = T4u[(size_t)(p.y & 1023u) * 16 + l16];
            float c = __uint_as_float(p.x);
            UNPACK_FMA(a, c, t)
        }
        // combine even/odd halves
#pragma unroll
        for (int j = 0; j < 8; ++j) a[j] += __shfl_xor(a[j], 16, 64);

        // overflow tail (n > CAP): half0 only, after combine (correctness fallback)
        if (n > CAP && half == 0) {
            float da_in = 0.f, da_out = 0.f;
            if (row < nent) { da_in = dinvAll[row]; da_out = dinvAll[nent + row]; }
            for (unsigned j2 = start + (unsigned)nin; j2 < end; ++j2) {
                uint2 p = payload[j2];
                if (((p.y >> 10) & 63u) == (unsigned)r) {
                    unsigned ty = p.y & 1023u;
                    bool f = ty < unrel;
                    float c = 0.5f * (f ? da_in : da_out) * dinvAll[(f ? 0 : nent) + p.x];
                    uint4 t = T4u[(size_t)ty * 16 + l16];
                    UNPACK_FMA(a, c, t)
                }
            }
        }

        if (half == 0 && row < nent) {
            out4[(size_t)row * 32 + l16 * 2]     = make_float4(a[0], a[1], a[2], a[3]);
            out4[(size_t)row * 32 + l16 * 2 + 1] = make_float4(a[4], a[5], a[6], a[7]);
#pragma unroll
            for (int j = 0; j < 8; ++j) { sacc[j] += a[j]; qacc[j] += a[j] * a[j]; }
        }
    }
    if (half == 0) {
#pragma unroll
        for (int j = 0; j < 8; ++j) {
            atomicAdd(&ls[8 * l16 + j], sacc[j]);
            atomicAdd(&lq[8 * l16 + j], qacc[j]);
        }
    }
    __syncthreads();
    if (tid < D) {
        atomicAdd(&sums[tid], ls[tid]);
        atomicAdd(&sumsq[tid], lq[tid]);
    }
}

// ---------------- fallback (atomic) path kernels ----------------
__global__ __launch_bounds__(256) void degree_kernel(const int* __restrict__ rows, int E,
                                                     float* __restrict__ deg_in,
                                                     float* __restrict__ deg_out) {
    int total = 2 * E;
    int tid = blockIdx.x * blockDim.x + threadIdx.x;
    int nth = gridDim.x * blockDim.x;
    for (long b = (long)tid * BUNROLL; b < total; b += (long)nth * BUNROLL) {
        for (int k = 0; k < BUNROLL && b + k < total; ++k) {
            int r = rows[b + k];
            float* deg = (b + k < E) ? deg_in : deg_out;
            atomicAdd(&deg[r], 1.0f);
        }
    }
}

__global__ void scatter_kernel(const int* __restrict__ rows, const int* __restrict__ cols,
                               const int* __restrict__ etype,
                               const float* __restrict__ deg_in, const float* __restrict__ deg_out,
                               const float* __restrict__ T_in, const float* __restrict__ T_out,
                               float* __restrict__ out, int E) {
    int wave = (blockIdx.x * blockDim.x + threadIdx.x) >> 6;
    int lane = threadIdx.x & 63;
    int nwaves = (gridDim.x * blockDim.x) >> 6;
    int total = 2 * E;
    for (int e = wave; e < total; e += nwaves) {
        bool first = (e < E);
        int row = rows[e];
        int col = cols[e];
        int t = etype[e];
        const float* deg = first ? deg_in : deg_out;
        const float* T = first ? T_in : T_out;
        float dr = deg[row];
        float dc = deg[col];
        float norm = (dr > 0.f ? rsqrtf(dr) : 0.f) * (dc > 0.f ? rsqrtf(dc) : 0.f);
        float c = 0.5f * norm;
        if (c != 0.f) {
            float v0 = c * T[t * D + lane];
            float v1 = c * T[t * D + 64 + lane];
            long b = (long)row * D;
            atomicAdd(&out[b + lane], v0);
            atomicAdd(&out[b + 64 + lane], v1);
        }
    }
}

__global__ void bn_stats_kernel(const float* __restrict__ h, int nent,
                                float* __restrict__ sums, float* __restrict__ sumsq) {
    int col = threadIdx.x;
    float s = 0.f, s2 = 0.f;
    for (int r = blockIdx.x; r < nent; r += gridDim.x) {
        float v = h[(long)r * D + col];
        s += v;
        s2 += v * v;
    }
    atomicAdd(&sums[col], s);
    atomicAdd(&sumsq[col], s2);
}

// ---------------- BN apply (both paths) ----------------
__global__ void bn_apply_kernel(float* __restrict__ h,
                                const float* __restrict__ sums, const float* __restrict__ sumsq,
                                const float* __restrict__ gamma, const float* __restrict__ beta,
                                int nent) {
    long total = ((long)nent * D) / 4;
    long stride = (long)gridDim.x * blockDim.x;
    float inv_n = 1.0f / (float)nent;
    float4* h4 = (float4*)h;
    for (long i = (long)blockIdx.x * blockDim.x + threadIdx.x; i < total; i += stride) {
        int c0 = (int)((i * 4) & (D - 1));
        float4 v = h4[i];
        float r[4] = {v.x, v.y, v.z, v.w};
#pragma unroll
        for (int j = 0; j < 4; ++j) {
            int col = c0 + j;
            float mean = sums[col] * inv_n;
            float var = sumsq[col] * inv_n - mean * mean;
            float istd = rsqrtf(var + 1e-5f);
            r[j] = tanhf((r[j] - mean) * istd * gamma[col] + beta[col]);
        }
        h4[i] = make_float4(r[0], r[1], r[2], r[3]);
    }
}

extern "C" void kernel_launch(void* const* d_in, const int* in_sizes, int n_in,
                              void* d_out, int out_size, void* d_ws, size_t ws_size,
                              hipStream_t stream) {
    const float* rel_embed     = (const float*)d_in[0];
    const float* rel_embed_in  = (const float*)d_in[1];
    const float* rel_embed_out = (const float*)d_in[2];
    const float* w_in          = (const float*)d_in[3];
    const float* w_out         = (const float*)d_in[4];
    const float* bn_gamma      = (const float*)d_in[5];
    const float* bn_beta       = (const float*)d_in[6];
    const int*   edge_index    = (const int*)d_in[7];
    const int*   edge_type     = (const int*)d_in[8];

    const int nrel = in_sizes[0] / D;               // 500
    const int E2   = in_sizes[8];                   // 3,000,000
    const int E    = E2 / 2;                        // 1,500,000
    const int nent = (out_size - in_sizes[0]) / D;  // 200,000
    const int K    = (nent + RPB - 1) / RPB;        // 3125 buckets
    const int NB   = (E2 + CHUNK4 - 1) / CHUNK4;    // 184 blocks
    const long NBK = (long)NB * K;                  // ~575K counters
    const int ntiles = (int)((NBK + STILE - 1) / STILE);  // ~562

    float* out = (float*)d_out;
    const int* rows = edge_index;
    const int* cols = edge_index + E2;

    // ---- workspace layout (fast path) ----
    float*          ws       = (float*)d_ws;
    float*          dinvAll  = ws;                                   // 2*nent
    float*          sums     = dinvAll + (size_t)2 * nent;           // D
    float*          sumsq    = sums + D;                             // D
    unsigned*       rowBase  = (unsigned*)(sumsq + D);               // K*RPB
    unsigned*       cnt      = rowBase + (size_t)K * RPB;            // NBK+1 (scan in place)
    unsigned*       tsum     = cnt + NBK + 1;                        // ntiles
    unsigned*       toff     = tsum + ntiles;                        // ntiles
    unsigned short* T_bf     = (unsigned short*)(toff + ntiles);     // 2*nrel*D bf16
    uintptr_t pal = ((uintptr_t)(T_bf + (size_t)2 * nrel * D) + 15) & ~(uintptr_t)15;
    uint2*          payload  = (uint2*)pal;                          // E2
    size_t needed = (pal + (size_t)E2 * sizeof(uint2)) - (uintptr_t)d_ws;

    bool fast = (needed <= ws_size) && (K <= MAXK) && (2 * nrel <= 1024) &&
                (ntiles <= 1024);

    if (fast) {
        hipMemsetAsync(sums, 0, (size_t)2 * D * sizeof(float), stream);

        transform2_bf_kernel<<<2 * nrel, D, 0, stream>>>(rel_embed_in, w_in,
                                                         rel_embed_out, w_out, T_bf, nrel);
        hist4_kernel<<<NB, 512, 0, stream>>>(rows, E2, cnt, NB, K);
        tile_sum_u32<<<ntiles, 256, 0, stream>>>(cnt, tsum, (int)NBK);
        scan_tiles_kernel<<<1, 1024, 0, stream>>>(tsum, toff, cnt, ntiles, (int)NBK);
        base_write_u32<<<ntiles, 256, 0, stream>>>(cnt, toff, cnt, (int)NBK);
        scatter4_kernel<<<NB, 512, 0, stream>>>(rows, cols, edge_type, cnt,
                                                payload, E, E2, nrel, NB, K);
        degsort_kernel<<<K, 512, 0, stream>>>(cnt, payload, dinvAll, rowBase,
                                              nent, nrel, NB, K);
        accum4_kernel<<<K, 512, 0, stream>>>(cnt, payload, T_bf, dinvAll, rowBase,
                                             out, sums, sumsq, nent, nrel, NB, K);
        bn_apply_kernel<<<4096, 256, 0, stream>>>(out, sums, sumsq, bn_gamma, bn_beta, nent);
    } else {
        // ---------- fallback atomic path (f32 everywhere) ----------
        float* f_deg_in  = ws;
        float* f_deg_out = f_deg_in + nent;
        float* f_T_in    = f_deg_out + nent;
        float* f_T_out   = f_T_in + (size_t)nrel * D;
        float* f_sums    = f_T_out + (size_t)nrel * D;
        float* f_sumsq   = f_sums + D;

        hipMemsetAsync(out, 0, (size_t)nent * D * sizeof(float), stream);
        hipMemsetAsync(f_deg_in, 0, (size_t)2 * nent * sizeof(float), stream);
        hipMemsetAsync(f_sums, 0, (size_t)2 * D * sizeof(float), stream);

        transform2_kernel<<<2 * nrel, D, 0, stream>>>(rel_embed_in, w_in, rel_embed_out, w_out,
                                                      f_T_in, nrel);
        degree_kernel<<<1466, 256, 0, stream>>>(edge_index, E, f_deg_in, f_deg_out);
        scatter_kernel<<<2048, 256, 0, stream>>>(rows, cols, edge_type, f_deg_in, f_deg_out,
                                                 f_T_in, f_T_out, out, E);
        bn_stats_kernel<<<1024, D, 0, stream>>>(out, nent, f_sums, f_sumsq);
        bn_apply_kernel<<<4096, 256, 0, stream>>>(out, f_sums, f_sumsq, bn_gamma, bn_beta, nent);
    }

    hipMemcpyAsync(out + (size_t)nent * D, rel_embed,
                   (size_t)nrel * D * sizeof(float), hipMemcpyDeviceToDevice, stream);
}

// Round 14
// 227.235 us; speedup vs baseline: 1.4211x; 1.4211x over previous
//
#include <hip/hip_runtime.h>

#define D 128
#define BUNROLL 8
#define RPB 128                 // rows per bucket
#define CAP 2560                // max edges sorted in LDS per bucket (avg ~1920)
#define MAXK 2048               // max buckets (LDS histogram size)
#define CHUNK4 8192             // edges per block in hist4/scatter4 (identical mapping!)
#define STILE 1024              // scan tile

__device__ __forceinline__ unsigned f2bf_rne(float x) {
    unsigned u = __float_as_uint(x);
    return (u + 0x7fffu + ((u >> 16) & 1u)) >> 16;
}

// ---------------- relation transform -> bf16 table (fast path) ----------------
__global__ void transform2_bf_kernel(const float* __restrict__ Rin, const float* __restrict__ Win,
                                     const float* __restrict__ Rout, const float* __restrict__ Wout,
                                     unsigned short* __restrict__ T_bf, int nrel) {
    __shared__ float row[D];
    int b = blockIdx.x;
    bool second = (b >= nrel);
    const float* R = second ? Rout : Rin;
    const float* W = second ? Wout : Win;
    int r = second ? b - nrel : b;
    int t = threadIdx.x;
    row[t] = R[r * D + t];
    __syncthreads();
    float acc = 0.f;
#pragma unroll 8
    for (int k = 0; k < D; ++k) acc += row[k] * W[k * D + t];
    T_bf[(size_t)b * D + t] = (unsigned short)f2bf_rne(acc);
}

// f32 version (fallback path)
__global__ void transform2_kernel(const float* __restrict__ Rin, const float* __restrict__ Win,
                                  const float* __restrict__ Rout, const float* __restrict__ Wout,
                                  float* __restrict__ T_all, int nrel) {
    __shared__ float row[D];
    int b = blockIdx.x;
    bool second = (b >= nrel);
    const float* R = second ? Rout : Rin;
    const float* W = second ? Wout : Win;
    int r = second ? b - nrel : b;
    int t = threadIdx.x;
    row[t] = R[r * D + t];
    __syncthreads();
    float acc = 0.f;
#pragma unroll 8
    for (int k = 0; k < D; ++k) acc += row[k] * W[k * D + t];
    T_all[(size_t)b * D + t] = acc;
}

// ---------------- pass 1: per-block LDS bucket histogram (int4 loads, NO global atomics) ----
__global__ __launch_bounds__(512) void hist4_kernel(
        const int* __restrict__ rows, int E2,
        unsigned* __restrict__ cnt, int NB, int K) {
    __shared__ unsigned h[MAXK];
    int tid = threadIdx.x, blk = blockIdx.x;
    for (int i = tid; i < K; i += 512) h[i] = 0;
    __syncthreads();
    long s = (long)blk * CHUNK4;
    long e = s + CHUNK4; if (e > E2) e = E2;
    long n = e - s;
    if ((n & 3) == 0) {
        const int4* r4 = (const int4*)(rows + s);
        int m = (int)(n >> 2);
        for (int i = tid; i < m; i += 512) {
            int4 r = r4[i];
            atomicAdd(&h[((unsigned)r.x) >> 7], 1u);
            atomicAdd(&h[((unsigned)r.y) >> 7], 1u);
            atomicAdd(&h[((unsigned)r.z) >> 7], 1u);
            atomicAdd(&h[((unsigned)r.w) >> 7], 1u);
        }
    } else {
        for (long i = s + tid; i < e; i += 512)
            atomicAdd(&h[((unsigned)rows[i]) >> 7], 1u);
    }
    __syncthreads();
    for (int i = tid; i < K; i += 512)
        cnt[(size_t)i * NB + blk] = h[i];
}

// ---------------- device-wide scan over n=NB*K counters ----------------
__global__ __launch_bounds__(256) void tile_sum_u32(const unsigned int* __restrict__ cnt,
                                                    unsigned int* __restrict__ tsum, int n) {
    int tid = threadIdx.x;
    int i0 = blockIdx.x * STILE + tid * 4;
    unsigned int s = 0;
#pragma unroll
    for (int k = 0; k < 4; ++k) {
        int i = i0 + k;
        if (i < n) s += cnt[i];
    }
    __shared__ unsigned int ls[256];
    ls[tid] = s;
    __syncthreads();
    for (int off = 128; off >= 1; off >>= 1) {
        if (tid < off) ls[tid] += ls[tid + off];
        __syncthreads();
    }
    if (tid == 0) tsum[blockIdx.x] = ls[0];
}

__global__ void scan_tiles_kernel(const unsigned int* __restrict__ tile_sums,
                                  unsigned int* __restrict__ tile_off,
                                  unsigned int* __restrict__ base, int ntiles, int n) {
    int t = threadIdx.x; // blockDim = 1024
    __shared__ unsigned int ls[1024];
    unsigned int v = (t < ntiles) ? tile_sums[t] : 0u;
    ls[t] = v;
    __syncthreads();
    for (int off = 1; off < 1024; off <<= 1) {
        unsigned int add = (t >= off) ? ls[t - off] : 0u;
        __syncthreads();
        ls[t] += add;
        __syncthreads();
    }
    if (t < ntiles) tile_off[t] = ls[t] - v; // exclusive
    if (t == 1023) base[n] = ls[1023];       // grand total
}

// in-place safe when base==cnt
__global__ __launch_bounds__(256) void base_write_u32(const unsigned int* __restrict__ cnt,
                                                      const unsigned int* __restrict__ tile_off,
                                                      unsigned int* __restrict__ base, int n) {
    int tid = threadIdx.x;
    int i0 = blockIdx.x * STILE + tid * 4;
    unsigned int c[4];
#pragma unroll
    for (int k = 0; k < 4; ++k) {
        int i = i0 + k;
        c[k] = (i < n) ? cnt[i] : 0u;
    }
    unsigned int s = c[0] + c[1] + c[2] + c[3];
    __shared__ unsigned int ls[256];
    ls[tid] = s;
    __syncthreads();
    for (int off = 1; off < 256; off <<= 1) {
        unsigned int add = (tid >= off) ? ls[tid - off] : 0u;
        __syncthreads();
        ls[tid] += add;
        __syncthreads();
    }
    unsigned int run = (tid > 0 ? ls[tid - 1] : 0u) + tile_off[blockIdx.x];
#pragma unroll
    for (int k = 0; k < 4; ++k) {
        int i = i0 + k;
        if (i < n) base[i] = run;
        run += c[k];
    }
}

// ---------------- pass 2: scatter with LDS ranks (int4 loads, NO global atomics) ----------
// payload = (col, (row&127)<<10 | type)
__global__ __launch_bounds__(512) void scatter4_kernel(
        const int* __restrict__ rows, const int* __restrict__ cols,
        const int* __restrict__ etype, const unsigned* __restrict__ base,
        uint2* __restrict__ payload, int E, int E2, int nrel, int NB, int K) {
    __shared__ unsigned cur[MAXK];
    int tid = threadIdx.x, blk = blockIdx.x;
    for (int i = tid; i < K; i += 512) cur[i] = base[(size_t)i * NB + blk];
    __syncthreads();
    long s = (long)blk * CHUNK4;
    long e = s + CHUNK4; if (e > E2) e = E2;
    long n = e - s;
    if ((n & 3) == 0) {
        const int4* r4 = (const int4*)(rows + s);
        const int4* c4 = (const int4*)(cols + s);
        const int4* t4 = (const int4*)(etype + s);
        int m = (int)(n >> 2);
        for (int i = tid; i < m; i += 512) {
            int4 r = r4[i];
            int4 c = c4[i];
            int4 t = t4[i];
            long e0 = s + ((long)i << 2);
            unsigned pos, ty;
            ty = (unsigned)t.x + ((e0 + 0 < E) ? 0u : (unsigned)nrel);
            pos = atomicAdd(&cur[((unsigned)r.x) >> 7], 1u);
            payload[pos] = make_uint2((unsigned)c.x, (((unsigned)r.x & 127u) << 10) | ty);
            ty = (unsigned)t.y + ((e0 + 1 < E) ? 0u : (unsigned)nrel);
            pos = atomicAdd(&cur[((unsigned)r.y) >> 7], 1u);
            payload[pos] = make_uint2((unsigned)c.y, (((unsigned)r.y & 127u) << 10) | ty);
            ty = (unsigned)t.z + ((e0 + 2 < E) ? 0u : (unsigned)nrel);
            pos = atomicAdd(&cur[((unsigned)r.z) >> 7], 1u);
            payload[pos] = make_uint2((unsigned)c.z, (((unsigned)r.z & 127u) << 10) | ty);
            ty = (unsigned)t.w + ((e0 + 3 < E) ? 0u : (unsigned)nrel);
            pos = atomicAdd(&cur[((unsigned)r.w) >> 7], 1u);
            payload[pos] = make_uint2((unsigned)c.w, (((unsigned)r.w & 127u) << 10) | ty);
        }
    } else {
        for (long i = s + tid; i < e; i += 512) {
            unsigned r = (unsigned)rows[i];
            unsigned c = (unsigned)cols[i];
            unsigned t = (unsigned)etype[i];
            unsigned ty = t + ((i < E) ? 0u : (unsigned)nrel);
            unsigned pos = atomicAdd(&cur[r >> 7], 1u);
            payload[pos] = make_uint2(c, ((r & 127u) << 10) | ty);
        }
    }
}

// ---------------- degrees + per-bucket row offsets from sorted payload ----------------
__global__ __launch_bounds__(512) void degsort_kernel(
        const unsigned* __restrict__ base, const uint2* __restrict__ payload,
        float* __restrict__ dinvAll, unsigned* __restrict__ rowBase,
        int nent, int nrel, int NB, int K) {
    __shared__ unsigned h2[RPB * 2];
    __shared__ unsigned sc[RPB];
    int tid = threadIdx.x, b = blockIdx.x;
    if (tid < RPB * 2) h2[tid] = 0;
    __syncthreads();
    size_t NBK = (size_t)NB * K;
    unsigned s = base[(size_t)b * NB];
    unsigned e = (b + 1 < K) ? base[(size_t)(b + 1) * NB] : base[NBK];
    for (unsigned i = s + tid; i < e; i += 512) {
        unsigned y = payload[i].y;
        unsigned lr = (y >> 10) & 127u;
        unsigned fo = ((y & 1023u) >= (unsigned)nrel) ? 1u : 0u;
        atomicAdd(&h2[lr * 2 + fo], 1u);
    }
    __syncthreads();
    unsigned tot = 0;
    if (tid < RPB) { tot = h2[tid * 2] + h2[tid * 2 + 1]; sc[tid] = tot; }
    __syncthreads();
    for (int off = 1; off < RPB; off <<= 1) {
        unsigned v = 0;
        if (tid < RPB && tid >= off) v = sc[tid - off];
        __syncthreads();
        if (tid < RPB) sc[tid] += v;
        __syncthreads();
    }
    if (tid < RPB) {
        rowBase[(size_t)b * RPB + tid] = sc[tid] - tot;   // exclusive prefix
        int row = (b << 7) + tid;
        if (row < nent) {
            unsigned a = h2[tid * 2], o = h2[tid * 2 + 1];
            dinvAll[row]        = a ? rsqrtf((float)a) : 0.f;
            dinvAll[nent + row] = o ? rsqrtf((float)o) : 0.f;
        }
    }
}

// ---------------- per-bucket reorder + register accumulate (bf16 T) + fused BN stats ------
// (R11 configuration: 32-lane groups, uint2 T loads, per-lane dinv — best measured)
__global__ __launch_bounds__(512) void accum4_kernel(
        const unsigned* __restrict__ base, const uint2* __restrict__ payload,
        const unsigned short* __restrict__ T_bf, const float* __restrict__ dinvAll,
        const unsigned* __restrict__ rowBase,
        float* __restrict__ out, float* __restrict__ sums, float* __restrict__ sumsq,
        int nent, int nrel, int NB, int K) {
    __shared__ uint2 sp[CAP];              // 20 KB
    __shared__ unsigned hstart[RPB];
    __shared__ unsigned hcur[RPB];
    __shared__ float ls[D], lq[D];
    int tid = threadIdx.x;
    int b = blockIdx.x;
    size_t NBK = (size_t)NB * K;
    unsigned start = base[(size_t)b * NB];
    unsigned end   = (b + 1 < K) ? base[(size_t)(b + 1) * NB] : base[NBK];
    int n = (int)(end - start);
    int nin = n < CAP ? n : CAP;

    if (tid < RPB) { ls[tid] = 0.f; lq[tid] = 0.f; }

    if (n <= CAP) {
        if (tid < RPB) {
            unsigned v = rowBase[(size_t)b * RPB + tid];
            hstart[tid] = v;
            hcur[tid] = v;
        }
        __syncthreads();
        for (int i = tid; i < nin; i += 512) {
            uint2 p = payload[start + i];
            unsigned pos = atomicAdd(&hcur[(p.y >> 10) & 127u], 1u);
            sp[pos] = p;
        }
        __syncthreads();
    } else {
        if (tid < RPB) hstart[tid] = 0;
        __syncthreads();
        for (int i = tid; i < nin; i += 512)
            atomicAdd(&hstart[(payload[start + i].y >> 10) & 127u], 1u);
        __syncthreads();
        for (int off = 1; off < RPB; off <<= 1) {
            unsigned v = 0;
            if (tid < RPB && tid >= off) v = hstart[tid - off];
            __syncthreads();
            if (tid < RPB) hstart[tid] += v;
            __syncthreads();
        }
        unsigned ex = 0;
        if (tid < RPB) ex = tid ? hstart[tid - 1] : 0u;
        __syncthreads();
        if (tid < RPB) { hstart[tid] = ex; hcur[tid] = ex; }
        __syncthreads();
        for (int i = tid; i < nin; i += 512) {
            uint2 p = payload[start + i];
            unsigned pos = atomicAdd(&hcur[(p.y >> 10) & 127u], 1u);
            sp[pos] = p;
        }
        __syncthreads();
    }

    const uint2* T2 = (const uint2*)T_bf;   // one row = 128 bf16 = 32 uint2
    float4* out4 = (float4*)out;
    int hw = tid >> 5, l32 = tid & 31;
    int row0 = b << 7;
    unsigned unrel = (unsigned)nrel;
    float4 s4 = make_float4(0.f, 0.f, 0.f, 0.f);
    float4 q4 = make_float4(0.f, 0.f, 0.f, 0.f);
    for (int rr = 0; rr < 8; ++rr) {
        int r = (hw << 3) + rr;
        int row = row0 + r;
        float da_in = 0.f, da_out = 0.f;
        if (row < nent) { da_in = dinvAll[row]; da_out = dinvAll[nent + row]; }
        unsigned s0 = hstart[r];
        unsigned s1 = (r < RPB - 1) ? hstart[r + 1] : (unsigned)nin;
        float4 a = make_float4(0.f, 0.f, 0.f, 0.f);
        unsigned i = s0;
        for (; i + 4 <= s1; i += 4) {      // 4-deep independent chains
            uint2 p0 = sp[i], p1 = sp[i + 1], p2 = sp[i + 2], p3 = sp[i + 3];
            unsigned ty0 = p0.y & 1023u, ty1 = p1.y & 1023u;
            unsigned ty2 = p2.y & 1023u, ty3 = p3.y & 1023u;
            bool f0 = ty0 < unrel, f1 = ty1 < unrel, f2 = ty2 < unrel, f3 = ty3 < unrel;
            float dc0 = dinvAll[(f0 ? 0 : nent) + p0.x];
            float dc1 = dinvAll[(f1 ? 0 : nent) + p1.x];
            float dc2 = dinvAll[(f2 ? 0 : nent) + p2.x];
            float dc3 = dinvAll[(f3 ? 0 : nent) + p3.x];
            uint2 t0 = T2[(size_t)ty0 * 32 + l32];
            uint2 t1 = T2[(size_t)ty1 * 32 + l32];
            uint2 t2 = T2[(size_t)ty2 * 32 + l32];
            uint2 t3 = T2[(size_t)ty3 * 32 + l32];
            float c0 = 0.5f * (f0 ? da_in : da_out) * dc0;
            float c1 = 0.5f * (f1 ? da_in : da_out) * dc1;
            float c2 = 0.5f * (f2 ? da_in : da_out) * dc2;
            float c3 = 0.5f * (f3 ? da_in : da_out) * dc3;
            a.x += c0 * __uint_as_float(t0.x << 16);
            a.y += c0 * __uint_as_float(t0.x & 0xffff0000u);
            a.z += c0 * __uint_as_float(t0.y << 16);
            a.w += c0 * __uint_as_float(t0.y & 0xffff0000u);
            a.x += c1 * __uint_as_float(t1.x << 16);
            a.y += c1 * __uint_as_float(t1.x & 0xffff0000u);
            a.z += c1 * __uint_as_float(t1.y << 16);
            a.w += c1 * __uint_as_float(t1.y & 0xffff0000u);
            a.x += c2 * __uint_as_float(t2.x << 16);
            a.y += c2 * __uint_as_float(t2.x & 0xffff0000u);
            a.z += c2 * __uint_as_float(t2.y << 16);
            a.w += c2 * __uint_as_float(t2.y & 0xffff0000u);
            a.x += c3 * __uint_as_float(t3.x << 16);
            a.y += c3 * __uint_as_float(t3.x & 0xffff0000u);
            a.z += c3 * __uint_as_float(t3.y << 16);
            a.w += c3 * __uint_as_float(t3.y & 0xffff0000u);
        }
        for (; i < s1; ++i) {
            uint2 p = sp[i];
            unsigned ty = p.y & 1023u;
            bool f = ty < unrel;
            float c = 0.5f * (f ? da_in : da_out) * dinvAll[(f ? 0 : nent) + p.x];
            uint2 t = T2[(size_t)ty * 32 + l32];
            a.x += c * __uint_as_float(t.x << 16);
            a.y += c * __uint_as_float(t.x & 0xffff0000u);
            a.z += c * __uint_as_float(t.y << 16);
            a.w += c * __uint_as_float(t.y & 0xffff0000u);
        }
        // overflow tail (n > CAP): correctness fallback
        for (unsigned j = start + (unsigned)nin; j < end; ++j) {
            uint2 p = payload[j];
            if (((p.y >> 10) & 127u) == (unsigned)r) {
                unsigned ty = p.y & 1023u;
                bool f = ty < unrel;
                float c = 0.5f * (f ? da_in : da_out) * dinvAll[(f ? 0 : nent) + p.x];
                uint2 t = T2[(size_t)ty * 32 + l32];
                a.x += c * __uint_as_float(t.x << 16);
                a.y += c * __uint_as_float(t.x & 0xffff0000u);
                a.z += c * __uint_as_float(t.y << 16);
                a.w += c * __uint_as_float(t.y & 0xffff0000u);
            }
        }
        if (row < nent) {
            out4[(size_t)row * 32 + l32] = a;
            s4.x += a.x; s4.y += a.y; s4.z += a.z; s4.w += a.w;
            q4.x += a.x * a.x; q4.y += a.y * a.y; q4.z += a.z * a.z; q4.w += a.w * a.w;
        }
    }
    atomicAdd(&ls[4 * l32 + 0], s4.x); atomicAdd(&ls[4 * l32 + 1], s4.y);
    atomicAdd(&ls[4 * l32 + 2], s4.z); atomicAdd(&ls[4 * l32 + 3], s4.w);
    atomicAdd(&lq[4 * l32 + 0], q4.x); atomicAdd(&lq[4 * l32 + 1], q4.y);
    atomicAdd(&lq[4 * l32 + 2], q4.z); atomicAdd(&lq[4 * l32 + 3], q4.w);
    __syncthreads();
    if (tid < D) {
        atomicAdd(&sums[tid], ls[tid]);
        atomicAdd(&sumsq[tid], lq[tid]);
    }
}

// ---------------- BN coefficient hoisting + apply ----------------
__global__ void bn_coef_kernel(const float* __restrict__ sums, const float* __restrict__ sumsq,
                               const float* __restrict__ gamma, const float* __restrict__ beta,
                               float* __restrict__ scale, float* __restrict__ shift, int nent) {
    int c = threadIdx.x;  // 128
    float inv_n = 1.0f / (float)nent;
    float mean = sums[c] * inv_n;
    float var = sumsq[c] * inv_n - mean * mean;
    float istd = rsqrtf(var + 1e-5f);
    float sc = istd * gamma[c];
    scale[c] = sc;
    shift[c] = beta[c] - mean * sc;
}

// tanh(v*scale+shift) in place + fused rel_embed passthrough
__global__ __launch_bounds__(256) void bn_apply2_kernel(
        float* __restrict__ h, const float* __restrict__ scale, const float* __restrict__ shift,
        const float* __restrict__ rel_embed, float* __restrict__ pass, int nent, int npass4) {
    __shared__ float s_sc[D], s_sh[D];
    if (threadIdx.x < D) { s_sc[threadIdx.x] = scale[threadIdx.x]; s_sh[threadIdx.x] = shift[threadIdx.x]; }
    __syncthreads();
    long total = (long)nent * (D / 4);
    long stride = (long)gridDim.x * blockDim.x;
    long idx0 = (long)blockIdx.x * blockDim.x + threadIdx.x;
    float4* h4 = (float4*)h;
    for (long i = idx0; i < total; i += stride) {
        int c0 = (int)((i & 31) << 2);
        float4 v = h4[i];
        v.x = tanhf(v.x * s_sc[c0 + 0] + s_sh[c0 + 0]);
        v.y = tanhf(v.y * s_sc[c0 + 1] + s_sh[c0 + 1]);
        v.z = tanhf(v.z * s_sc[c0 + 2] + s_sh[c0 + 2]);
        v.w = tanhf(v.w * s_sc[c0 + 3] + s_sh[c0 + 3]);
        h4[i] = v;
    }
    const float4* re4 = (const float4*)rel_embed;
    float4* p4 = (float4*)pass;
    for (long i = idx0; i < npass4; i += stride) p4[i] = re4[i];
}

// ---------------- fallback (atomic) path kernels ----------------
__global__ __launch_bounds__(256) void degree_kernel(const int* __restrict__ rows, int E,
                                                     float* __restrict__ deg_in,
                                                     float* __restrict__ deg_out) {
    int total = 2 * E;
    int tid = blockIdx.x * blockDim.x + threadIdx.x;
    int nth = gridDim.x * blockDim.x;
    for (long b = (long)tid * BUNROLL; b < total; b += (long)nth * BUNROLL) {
        for (int k = 0; k < BUNROLL && b + k < total; ++k) {
            int r = rows[b + k];
            float* deg = (b + k < E) ? deg_in : deg_out;
            atomicAdd(&deg[r], 1.0f);
        }
    }
}

__global__ void scatter_kernel(const int* __restrict__ rows, const int* __restrict__ cols,
                               const int* __restrict__ etype,
                               const float* __restrict__ deg_in, const float* __restrict__ deg_out,
                               const float* __restrict__ T_in, const float* __restrict__ T_out,
                               float* __restrict__ out, int E) {
    int wave = (blockIdx.x * blockDim.x + threadIdx.x) >> 6;
    int lane = threadIdx.x & 63;
    int nwaves = (gridDim.x * blockDim.x) >> 6;
    int total = 2 * E;
    for (int e = wave; e < total; e += nwaves) {
        bool first = (e < E);
        int row = rows[e];
        int col = cols[e];
        int t = etype[e];
        const float* deg = first ? deg_in : deg_out;
        const float* T = first ? T_in : T_out;
        float dr = deg[row];
        float dc = deg[col];
        float norm = (dr > 0.f ? rsqrtf(dr) : 0.f) * (dc > 0.f ? rsqrtf(dc) : 0.f);
        float c = 0.5f * norm;
        if (c != 0.f) {
            float v0 = c * T[t * D + lane];
            float v1 = c * T[t * D + 64 + lane];
            long b = (long)row * D;
            atomicAdd(&out[b + lane], v0);
            atomicAdd(&out[b + 64 + lane], v1);
        }
    }
}

__global__ void bn_stats_kernel(const float* __restrict__ h, int nent,
                                float* __restrict__ sums, float* __restrict__ sumsq) {
    int col = threadIdx.x;
    float s = 0.f, s2 = 0.f;
    for (int r = blockIdx.x; r < nent; r += gridDim.x) {
        float v = h[(long)r * D + col];
        s += v;
        s2 += v * v;
    }
    atomicAdd(&sums[col], s);
    atomicAdd(&sumsq[col], s2);
}

__global__ void bn_apply_kernel(float* __restrict__ h,
                                const float* __restrict__ sums, const float* __restrict__ sumsq,
                                const float* __restrict__ gamma, const float* __restrict__ beta,
                                int nent) {
    long total = ((long)nent * D) / 4;
    long stride = (long)gridDim.x * blockDim.x;
    float inv_n = 1.0f / (float)nent;
    float4* h4 = (float4*)h;
    for (long i = (long)blockIdx.x * blockDim.x + threadIdx.x; i < total; i += stride) {
        int c0 = (int)((i * 4) & (D - 1));
        float4 v = h4[i];
        float r[4] = {v.x, v.y, v.z, v.w};
#pragma unroll
        for (int j = 0; j < 4; ++j) {
            int col = c0 + j;
            float mean = sums[col] * inv_n;
            float var = sumsq[col] * inv_n - mean * mean;
            float istd = rsqrtf(var + 1e-5f);
            r[j] = tanhf((r[j] - mean) * istd * gamma[col] + beta[col]);
        }
        h4[i] = make_float4(r[0], r[1], r[2], r[3]);
    }
}

extern "C" void kernel_launch(void* const* d_in, const int* in_sizes, int n_in,
                              void* d_out, int out_size, void* d_ws, size_t ws_size,
                              hipStream_t stream) {
    const float* rel_embed     = (const float*)d_in[0];
    const float* rel_embed_in  = (const float*)d_in[1];
    const float* rel_embed_out = (const float*)d_in[2];
    const float* w_in          = (const float*)d_in[3];
    const float* w_out         = (const float*)d_in[4];
    const float* bn_gamma      = (const float*)d_in[5];
    const float* bn_beta       = (const float*)d_in[6];
    const int*   edge_index    = (const int*)d_in[7];
    const int*   edge_type     = (const int*)d_in[8];

    const int nrel = in_sizes[0] / D;               // 500
    const int E2   = in_sizes[8];                   // 3,000,000
    const int E    = E2 / 2;                        // 1,500,000
    const int nent = (out_size - in_sizes[0]) / D;  // 200,000
    const int K    = (nent + RPB - 1) / RPB;        // 1563 buckets
    const int NB   = (E2 + CHUNK4 - 1) / CHUNK4;    // 367 blocks
    const long NBK = (long)NB * K;                  // ~574K counters
    const int ntiles = (int)((NBK + STILE - 1) / STILE);  // ~561

    float* out = (float*)d_out;
    const int* rows = edge_index;
    const int* cols = edge_index + E2;

    // ---- workspace layout (fast path) ----
    float*          ws       = (float*)d_ws;
    float*          dinvAll  = ws;                                   // 2*nent
    float*          sums     = dinvAll + (size_t)2 * nent;           // D
    float*          sumsq    = sums + D;                             // D
    float*          scale    = sumsq + D;                            // D
    float*          shift    = scale + D;                            // D
    unsigned*       rowBase  = (unsigned*)(shift + D);               // K*RPB
    unsigned*       cnt      = rowBase + (size_t)K * RPB;            // NBK+1 (scan in place)
    unsigned*       tsum     = cnt + NBK + 1;                        // ntiles
    unsigned*       toff     = tsum + ntiles;                        // ntiles
    unsigned short* T_bf     = (unsigned short*)(toff + ntiles);     // 2*nrel*D bf16
    uintptr_t pal = ((uintptr_t)(T_bf + (size_t)2 * nrel * D) + 15) & ~(uintptr_t)15;
    uint2*          payload  = (uint2*)pal;                          // E2
    size_t needed = (pal + (size_t)E2 * sizeof(uint2)) - (uintptr_t)d_ws;

    bool fast = (needed <= ws_size) && (K <= MAXK) && (2 * nrel <= 1024) &&
                (ntiles <= 1024);

    if (fast) {
        hipMemsetAsync(sums, 0, (size_t)2 * D * sizeof(float), stream);

        transform2_bf_kernel<<<2 * nrel, D, 0, stream>>>(rel_embed_in, w_in,
                                                         rel_embed_out, w_out, T_bf, nrel);
        hist4_kernel<<<NB, 512, 0, stream>>>(rows, E2, cnt, NB, K);
        tile_sum_u32<<<ntiles, 256, 0, stream>>>(cnt, tsum, (int)NBK);
        scan_tiles_kernel<<<1, 1024, 0, stream>>>(tsum, toff, cnt, ntiles, (int)NBK);
        base_write_u32<<<ntiles, 256, 0, stream>>>(cnt, toff, cnt, (int)NBK);
        scatter4_kernel<<<NB, 512, 0, stream>>>(rows, cols, edge_type, cnt,
                                                payload, E, E2, nrel, NB, K);
        degsort_kernel<<<K, 512, 0, stream>>>(cnt, payload, dinvAll, rowBase,
                                              nent, nrel, NB, K);
        accum4_kernel<<<K, 512, 0, stream>>>(cnt, payload, T_bf, dinvAll, rowBase,
                                             out, sums, sumsq, nent, nrel, NB, K);
        bn_coef_kernel<<<1, D, 0, stream>>>(sums, sumsq, bn_gamma, bn_beta,
                                            scale, shift, nent);
        bn_apply2_kernel<<<2048, 256, 0, stream>>>(out, scale, shift, rel_embed,
                                                   out + (size_t)nent * D, nent,
                                                   (nrel * D) / 4);
    } else {
        // ---------- fallback atomic path (f32 everywhere) ----------
        float* f_deg_in  = ws;
        float* f_deg_out = f_deg_in + nent;
        float* f_T_in    = f_deg_out + nent;
        float* f_T_out   = f_T_in + (size_t)nrel * D;
        float* f_sums    = f_T_out + (size_t)nrel * D;
        float* f_sumsq   = f_sums + D;

        hipMemsetAsync(out, 0, (size_t)nent * D * sizeof(float), stream);
        hipMemsetAsync(f_deg_in, 0, (size_t)2 * nent * sizeof(float), stream);
        hipMemsetAsync(f_sums, 0, (size_t)2 * D * sizeof(float), stream);

        transform2_kernel<<<2 * nrel, D, 0, stream>>>(rel_embed_in, w_in, rel_embed_out, w_out,
                                                      f_T_in, nrel);
        degree_kernel<<<1466, 256, 0, stream>>>(edge_index, E, f_deg_in, f_deg_out);
        scatter_kernel<<<2048, 256, 0, stream>>>(rows, cols, edge_type, f_deg_in, f_deg_out,
                                                 f_T_in, f_T_out, out, E);
        bn_stats_kernel<<<1024, D, 0, stream>>>(out, nent, f_sums, f_sumsq);
        bn_apply_kernel<<<4096, 256, 0, stream>>>(out, f_sums, f_sumsq, bn_gamma, bn_beta, nent);
        hipMemcpyAsync(out + (size_t)nent * D, rel_embed,
                       (size_t)nrel * D * sizeof(float), hipMemcpyDeviceToDevice, stream);
    }
}

// Round 15
// 225.626 us; speedup vs baseline: 1.4312x; 1.0071x over previous
//
#include <hip/hip_runtime.h>

#define D 128
#define BUNROLL 8
#define RPB 128                 // rows per bucket
#define CAP 2560                // max edges sorted in LDS per bucket (avg ~1920)
#define MAXK 2048               // max buckets (LDS histogram size)
#define CHUNK4 8192             // edges per block in hist4/scatter4 (identical mapping!)
#define STILE 1024              // scan tile

__device__ __forceinline__ unsigned f2bf_rne(float x) {
    unsigned u = __float_as_uint(x);
    return (u + 0x7fffu + ((u >> 16) & 1u)) >> 16;
}

#define FMA4(a, c, t)                                        \
    (a).x += (c) * __uint_as_float((t).x << 16);             \
    (a).y += (c) * __uint_as_float((t).x & 0xffff0000u);     \
    (a).z += (c) * __uint_as_float((t).y << 16);             \
    (a).w += (c) * __uint_as_float((t).y & 0xffff0000u);

// ---------------- relation transform -> bf16 table (fast path) ----------------
__global__ void transform2_bf_kernel(const float* __restrict__ Rin, const float* __restrict__ Win,
                                     const float* __restrict__ Rout, const float* __restrict__ Wout,
                                     unsigned short* __restrict__ T_bf, int nrel) {
    __shared__ float row[D];
    int b = blockIdx.x;
    bool second = (b >= nrel);
    const float* R = second ? Rout : Rin;
    const float* W = second ? Wout : Win;
    int r = second ? b - nrel : b;
    int t = threadIdx.x;
    row[t] = R[r * D + t];
    __syncthreads();
    float acc = 0.f;
#pragma unroll 8
    for (int k = 0; k < D; ++k) acc += row[k] * W[k * D + t];
    T_bf[(size_t)b * D + t] = (unsigned short)f2bf_rne(acc);
}

// f32 version (fallback path)
__global__ void transform2_kernel(const float* __restrict__ Rin, const float* __restrict__ Win,
                                  const float* __restrict__ Rout, const float* __restrict__ Wout,
                                  float* __restrict__ T_all, int nrel) {
    __shared__ float row[D];
    int b = blockIdx.x;
    bool second = (b >= nrel);
    const float* R = second ? Rout : Rin;
    const float* W = second ? Wout : Win;
    int r = second ? b - nrel : b;
    int t = threadIdx.x;
    row[t] = R[r * D + t];
    __syncthreads();
    float acc = 0.f;
#pragma unroll 8
    for (int k = 0; k < D; ++k) acc += row[k] * W[k * D + t];
    T_all[(size_t)b * D + t] = acc;
}

// ---------------- pass 1: per-block LDS bucket histogram (int4 loads) ----------------
__global__ __launch_bounds__(512) void hist4_kernel(
        const int* __restrict__ rows, int E2,
        unsigned* __restrict__ cnt, int NB, int K) {
    __shared__ unsigned h[MAXK];
    int tid = threadIdx.x, blk = blockIdx.x;
    for (int i = tid; i < K; i += 512) h[i] = 0;
    __syncthreads();
    long s = (long)blk * CHUNK4;
    long e = s + CHUNK4; if (e > E2) e = E2;
    long n = e - s;
    if ((n & 3) == 0) {
        const int4* r4 = (const int4*)(rows + s);
        int m = (int)(n >> 2);
        for (int i = tid; i < m; i += 512) {
            int4 r = r4[i];
            atomicAdd(&h[((unsigned)r.x) >> 7], 1u);
            atomicAdd(&h[((unsigned)r.y) >> 7], 1u);
            atomicAdd(&h[((unsigned)r.z) >> 7], 1u);
            atomicAdd(&h[((unsigned)r.w) >> 7], 1u);
        }
    } else {
        for (long i = s + tid; i < e; i += 512)
            atomicAdd(&h[((unsigned)rows[i]) >> 7], 1u);
    }
    __syncthreads();
    for (int i = tid; i < K; i += 512)
        cnt[(size_t)i * NB + blk] = h[i];
}

// ---------------- device-wide scan over n=NB*K counters ----------------
__global__ __launch_bounds__(256) void tile_sum_u32(const unsigned int* __restrict__ cnt,
                                                    unsigned int* __restrict__ tsum, int n) {
    int tid = threadIdx.x;
    int i0 = blockIdx.x * STILE + tid * 4;
    unsigned int s = 0;
#pragma unroll
    for (int k = 0; k < 4; ++k) {
        int i = i0 + k;
        if (i < n) s += cnt[i];
    }
    __shared__ unsigned int ls[256];
    ls[tid] = s;
    __syncthreads();
    for (int off = 128; off >= 1; off >>= 1) {
        if (tid < off) ls[tid] += ls[tid + off];
        __syncthreads();
    }
    if (tid == 0) tsum[blockIdx.x] = ls[0];
}

__global__ void scan_tiles_kernel(const unsigned int* __restrict__ tile_sums,
                                  unsigned int* __restrict__ tile_off,
                                  unsigned int* __restrict__ base, int ntiles, int n) {
    int t = threadIdx.x; // blockDim = 1024
    __shared__ unsigned int ls[1024];
    unsigned int v = (t < ntiles) ? tile_sums[t] : 0u;
    ls[t] = v;
    __syncthreads();
    for (int off = 1; off < 1024; off <<= 1) {
        unsigned int add = (t >= off) ? ls[t - off] : 0u;
        __syncthreads();
        ls[t] += add;
        __syncthreads();
    }
    if (t < ntiles) tile_off[t] = ls[t] - v; // exclusive
    if (t == 1023) base[n] = ls[1023];       // grand total
}

// in-place safe when base==cnt
__global__ __launch_bounds__(256) void base_write_u32(const unsigned int* __restrict__ cnt,
                                                      const unsigned int* __restrict__ tile_off,
                                                      unsigned int* __restrict__ base, int n) {
    int tid = threadIdx.x;
    int i0 = blockIdx.x * STILE + tid * 4;
    unsigned int c[4];
#pragma unroll
    for (int k = 0; k < 4; ++k) {
        int i = i0 + k;
        c[k] = (i < n) ? cnt[i] : 0u;
    }
    unsigned int s = c[0] + c[1] + c[2] + c[3];
    __shared__ unsigned int ls[256];
    ls[tid] = s;
    __syncthreads();
    for (int off = 1; off < 256; off <<= 1) {
        unsigned int add = (tid >= off) ? ls[tid - off] : 0u;
        __syncthreads();
        ls[tid] += add;
        __syncthreads();
    }
    unsigned int run = (tid > 0 ? ls[tid - 1] : 0u) + tile_off[blockIdx.x];
#pragma unroll
    for (int k = 0; k < 4; ++k) {
        int i = i0 + k;
        if (i < n) base[i] = run;
        run += c[k];
    }
}

// ---------------- pass 2: scatter with LDS ranks (int4 loads) ----------------
// payload = (col, (row&127)<<10 | type)
__global__ __launch_bounds__(512) void scatter4_kernel(
        const int* __restrict__ rows, const int* __restrict__ cols,
        const int* __restrict__ etype, const unsigned* __restrict__ base,
        uint2* __restrict__ payload, int E, int E2, int nrel, int NB, int K) {
    __shared__ unsigned cur[MAXK];
    int tid = threadIdx.x, blk = blockIdx.x;
    for (int i = tid; i < K; i += 512) cur[i] = base[(size_t)i * NB + blk];
    __syncthreads();
    long s = (long)blk * CHUNK4;
    long e = s + CHUNK4; if (e > E2) e = E2;
    long n = e - s;
    if ((n & 3) == 0) {
        const int4* r4 = (const int4*)(rows + s);
        const int4* c4 = (const int4*)(cols + s);
        const int4* t4 = (const int4*)(etype + s);
        int m = (int)(n >> 2);
        for (int i = tid; i < m; i += 512) {
            int4 r = r4[i];
            int4 c = c4[i];
            int4 t = t4[i];
            long e0 = s + ((long)i << 2);
            unsigned pos, ty;
            ty = (unsigned)t.x + ((e0 + 0 < E) ? 0u : (unsigned)nrel);
            pos = atomicAdd(&cur[((unsigned)r.x) >> 7], 1u);
            payload[pos] = make_uint2((unsigned)c.x, (((unsigned)r.x & 127u) << 10) | ty);
            ty = (unsigned)t.y + ((e0 + 1 < E) ? 0u : (unsigned)nrel);
            pos = atomicAdd(&cur[((unsigned)r.y) >> 7], 1u);
            payload[pos] = make_uint2((unsigned)c.y, (((unsigned)r.y & 127u) << 10) | ty);
            ty = (unsigned)t.z + ((e0 + 2 < E) ? 0u : (unsigned)nrel);
            pos = atomicAdd(&cur[((unsigned)r.z) >> 7], 1u);
            payload[pos] = make_uint2((unsigned)c.z, (((unsigned)r.z & 127u) << 10) | ty);
            ty = (unsigned)t.w + ((e0 + 3 < E) ? 0u : (unsigned)nrel);
            pos = atomicAdd(&cur[((unsigned)r.w) >> 7], 1u);
            payload[pos] = make_uint2((unsigned)c.w, (((unsigned)r.w & 127u) << 10) | ty);
        }
    } else {
        for (long i = s + tid; i < e; i += 512) {
            unsigned r = (unsigned)rows[i];
            unsigned c = (unsigned)cols[i];
            unsigned t = (unsigned)etype[i];
            unsigned ty = t + ((i < E) ? 0u : (unsigned)nrel);
            unsigned pos = atomicAdd(&cur[r >> 7], 1u);
            payload[pos] = make_uint2(c, ((r & 127u) << 10) | ty);
        }
    }
}

// ---------------- degrees + per-bucket row offsets from sorted payload ----------------
__global__ __launch_bounds__(512) void degsort_kernel(
        const unsigned* __restrict__ base, const uint2* __restrict__ payload,
        float* __restrict__ dinvAll, unsigned* __restrict__ rowBase,
        int nent, int nrel, int NB, int K) {
    __shared__ unsigned h2[RPB * 2];
    __shared__ unsigned sc[RPB];
    int tid = threadIdx.x, b = blockIdx.x;
    if (tid < RPB * 2) h2[tid] = 0;
    __syncthreads();
    size_t NBK = (size_t)NB * K;
    unsigned s = base[(size_t)b * NB];
    unsigned e = (b + 1 < K) ? base[(size_t)(b + 1) * NB] : base[NBK];
    for (unsigned i = s + tid; i < e; i += 512) {
        unsigned y = payload[i].y;
        unsigned lr = (y >> 10) & 127u;
        unsigned fo = ((y & 1023u) >= (unsigned)nrel) ? 1u : 0u;
        atomicAdd(&h2[lr * 2 + fo], 1u);
    }
    __syncthreads();
    unsigned tot = 0;
    if (tid < RPB) { tot = h2[tid * 2] + h2[tid * 2 + 1]; sc[tid] = tot; }
    __syncthreads();
    for (int off = 1; off < RPB; off <<= 1) {
        unsigned v = 0;
        if (tid < RPB && tid >= off) v = sc[tid - off];
        __syncthreads();
        if (tid < RPB) sc[tid] += v;
        __syncthreads();
    }
    if (tid < RPB) {
        rowBase[(size_t)b * RPB + tid] = sc[tid] - tot;   // exclusive prefix
        int row = (b << 7) + tid;
        if (row < nent) {
            unsigned a = h2[tid * 2], o = h2[tid * 2 + 1];
            dinvAll[row]        = a ? rsqrtf((float)a) : 0.f;
            dinvAll[nent + row] = o ? rsqrtf((float)o) : 0.f;
        }
    }
}

// 4-deep pipelined drain of one segment [i, s1) into accumulator a
#define DRAIN4(i, s1, a, dain, daout)                                            \
    for (; (i) + 4 <= (s1); (i) += 4) {                                          \
        uint2 p0 = sp[(i)], p1 = sp[(i) + 1], p2 = sp[(i) + 2], p3 = sp[(i) + 3];\
        unsigned ty0 = p0.y & 1023u, ty1 = p1.y & 1023u;                         \
        unsigned ty2 = p2.y & 1023u, ty3 = p3.y & 1023u;                         \
        bool f0 = ty0 < unrel, f1 = ty1 < unrel;                                 \
        bool f2 = ty2 < unrel, f3 = ty3 < unrel;                                 \
        float dc0 = dinvAll[(f0 ? 0 : nent) + p0.x];                             \
        float dc1 = dinvAll[(f1 ? 0 : nent) + p1.x];                             \
        float dc2 = dinvAll[(f2 ? 0 : nent) + p2.x];                             \
        float dc3 = dinvAll[(f3 ? 0 : nent) + p3.x];                             \
        uint2 t0 = T2[(size_t)ty0 * 32 + l32];                                   \
        uint2 t1 = T2[(size_t)ty1 * 32 + l32];                                   \
        uint2 t2 = T2[(size_t)ty2 * 32 + l32];                                   \
        uint2 t3 = T2[(size_t)ty3 * 32 + l32];                                   \
        float c0 = 0.5f * (f0 ? (dain) : (daout)) * dc0;                         \
        float c1 = 0.5f * (f1 ? (dain) : (daout)) * dc1;                         \
        float c2 = 0.5f * (f2 ? (dain) : (daout)) * dc2;                         \
        float c3 = 0.5f * (f3 ? (dain) : (daout)) * dc3;                         \
        FMA4(a, c0, t0) FMA4(a, c1, t1) FMA4(a, c2, t2) FMA4(a, c3, t3)          \
    }                                                                            \
    for (; (i) < (s1); ++(i)) {                                                  \
        uint2 p = sp[(i)];                                                       \
        unsigned ty = p.y & 1023u;                                               \
        bool f = ty < unrel;                                                     \
        float c = 0.5f * (f ? (dain) : (daout)) * dinvAll[(f ? 0 : nent) + p.x]; \
        uint2 t = T2[(size_t)ty * 32 + l32];                                     \
        FMA4(a, c, t)                                                            \
    }

// ---------------- per-bucket reorder + DUAL-ROW register accumulate + BN stats ----------
__global__ __launch_bounds__(512) void accum4_kernel(
        const unsigned* __restrict__ base, const uint2* __restrict__ payload,
        const unsigned short* __restrict__ T_bf, const float* __restrict__ dinvAll,
        const unsigned* __restrict__ rowBase,
        float* __restrict__ out, unsigned short* __restrict__ h_bf, int use_bf,
        float* __restrict__ sums, float* __restrict__ sumsq,
        int nent, int nrel, int NB, int K) {
    __shared__ uint2 sp[CAP];              // 20 KB
    __shared__ unsigned hstart[RPB];
    __shared__ unsigned hcur[RPB];
    __shared__ float ls[D], lq[D];
    int tid = threadIdx.x;
    int b = blockIdx.x;
    size_t NBK = (size_t)NB * K;
    unsigned start = base[(size_t)b * NB];
    unsigned end   = (b + 1 < K) ? base[(size_t)(b + 1) * NB] : base[NBK];
    int n = (int)(end - start);
    int nin = n < CAP ? n : CAP;

    if (tid < RPB) { ls[tid] = 0.f; lq[tid] = 0.f; }

    if (n <= CAP) {
        if (tid < RPB) {
            unsigned v = rowBase[(size_t)b * RPB + tid];
            hstart[tid] = v;
            hcur[tid] = v;
        }
        __syncthreads();
        for (int i = tid; i < nin; i += 512) {
            uint2 p = payload[start + i];
            unsigned pos = atomicAdd(&hcur[(p.y >> 10) & 127u], 1u);
            sp[pos] = p;
        }
        __syncthreads();
    } else {
        if (tid < RPB) hstart[tid] = 0;
        __syncthreads();
        for (int i = tid; i < nin; i += 512)
            atomicAdd(&hstart[(payload[start + i].y >> 10) & 127u], 1u);
        __syncthreads();
        for (int off = 1; off < RPB; off <<= 1) {
            unsigned v = 0;
            if (tid < RPB && tid >= off) v = hstart[tid - off];
            __syncthreads();
            if (tid < RPB) hstart[tid] += v;
            __syncthreads();
        }
        unsigned ex = 0;
        if (tid < RPB) ex = tid ? hstart[tid - 1] : 0u;
        __syncthreads();
        if (tid < RPB) { hstart[tid] = ex; hcur[tid] = ex; }
        __syncthreads();
        for (int i = tid; i < nin; i += 512) {
            uint2 p = payload[start + i];
            unsigned pos = atomicAdd(&hcur[(p.y >> 10) & 127u], 1u);
            sp[pos] = p;
        }
        __syncthreads();
    }

    const uint2* T2 = (const uint2*)T_bf;   // one row = 128 bf16 = 32 uint2
    float4* out4 = (float4*)out;
    uint2* hb2 = (uint2*)h_bf;
    int hw = tid >> 5, l32 = tid & 31;
    int row0 = b << 7;
    unsigned unrel = (unsigned)nrel;
    float4 s4 = make_float4(0.f, 0.f, 0.f, 0.f);
    float4 q4 = make_float4(0.f, 0.f, 0.f, 0.f);

    for (int rp = 0; rp < 4; ++rp) {
        int rA = (hw << 3) + rp * 2;
        int rB = rA + 1;
        int rowA = row0 + rA, rowB = row0 + rB;
        float daA_in = 0.f, daA_out = 0.f, daB_in = 0.f, daB_out = 0.f;
        if (rowA < nent) { daA_in = dinvAll[rowA]; daA_out = dinvAll[nent + rowA]; }
        if (rowB < nent) { daB_in = dinvAll[rowB]; daB_out = dinvAll[nent + rowB]; }
        unsigned sA1 = hstart[rA + 1];                       // rA+1 = rB <= 127
        unsigned sB1 = (rB < RPB - 1) ? hstart[rB + 1] : (unsigned)nin;
        unsigned iA = hstart[rA], iB = sA1;
        float4 aA = make_float4(0.f, 0.f, 0.f, 0.f);
        float4 aB = make_float4(0.f, 0.f, 0.f, 0.f);

        // interleaved 2-deep chains on both rows (4 loads in flight)
        while (iA + 2 <= sA1 && iB + 2 <= sB1) {
            uint2 pA0 = sp[iA], pA1 = sp[iA + 1];
            uint2 pB0 = sp[iB], pB1 = sp[iB + 1];
            unsigned tyA0 = pA0.y & 1023u, tyA1 = pA1.y & 1023u;
            unsigned tyB0 = pB0.y & 1023u, tyB1 = pB1.y & 1023u;
            bool fA0 = tyA0 < unrel, fA1 = tyA1 < unrel;
            bool fB0 = tyB0 < unrel, fB1 = tyB1 < unrel;
            float dcA0 = dinvAll[(fA0 ? 0 : nent) + pA0.x];
            float dcA1 = dinvAll[(fA1 ? 0 : nent) + pA1.x];
            float dcB0 = dinvAll[(fB0 ? 0 : nent) + pB0.x];
            float dcB1 = dinvAll[(fB1 ? 0 : nent) + pB1.x];
            uint2 tA0 = T2[(size_t)tyA0 * 32 + l32];
            uint2 tA1 = T2[(size_t)tyA1 * 32 + l32];
            uint2 tB0 = T2[(size_t)tyB0 * 32 + l32];
            uint2 tB1 = T2[(size_t)tyB1 * 32 + l32];
            float cA0 = 0.5f * (fA0 ? daA_in : daA_out) * dcA0;
            float cA1 = 0.5f * (fA1 ? daA_in : daA_out) * dcA1;
            float cB0 = 0.5f * (fB0 ? daB_in : daB_out) * dcB0;
            float cB1 = 0.5f * (fB1 ? daB_in : daB_out) * dcB1;
            FMA4(aA, cA0, tA0) FMA4(aA, cA1, tA1)
            FMA4(aB, cB0, tB0) FMA4(aB, cB1, tB1)
            iA += 2; iB += 2;
        }
        // drain remainders (4-deep + scalar)
        DRAIN4(iA, sA1, aA, daA_in, daA_out)
        DRAIN4(iB, sB1, aB, daB_in, daB_out)

        // overflow tail (n > CAP): correctness fallback
        if (n > CAP) {
            for (unsigned j2 = start + (unsigned)nin; j2 < end; ++j2) {
                uint2 p = payload[j2];
                unsigned lr = (p.y >> 10) & 127u;
                if (lr == (unsigned)rA || lr == (unsigned)rB) {
                    unsigned ty = p.y & 1023u;
                    bool f = ty < unrel;
                    float dc = dinvAll[(f ? 0 : nent) + p.x];
                    uint2 t = T2[(size_t)ty * 32 + l32];
                    if (lr == (unsigned)rA) {
                        float c = 0.5f * (f ? daA_in : daA_out) * dc;
                        FMA4(aA, c, t)
                    } else {
                        float c = 0.5f * (f ? daB_in : daB_out) * dc;
                        FMA4(aB, c, t)
                    }
                }
            }
        }

        if (rowA < nent) {
            if (use_bf) {
                hb2[(size_t)rowA * 32 + l32] = make_uint2(
                    f2bf_rne(aA.x) | (f2bf_rne(aA.y) << 16),
                    f2bf_rne(aA.z) | (f2bf_rne(aA.w) << 16));
            } else {
                out4[(size_t)rowA * 32 + l32] = aA;
            }
            s4.x += aA.x; s4.y += aA.y; s4.z += aA.z; s4.w += aA.w;
            q4.x += aA.x * aA.x; q4.y += aA.y * aA.y;
            q4.z += aA.z * aA.z; q4.w += aA.w * aA.w;
        }
        if (rowB < nent) {
            if (use_bf) {
                hb2[(size_t)rowB * 32 + l32] = make_uint2(
                    f2bf_rne(aB.x) | (f2bf_rne(aB.y) << 16),
                    f2bf_rne(aB.z) | (f2bf_rne(aB.w) << 16));
            } else {
                out4[(size_t)rowB * 32 + l32] = aB;
            }
            s4.x += aB.x; s4.y += aB.y; s4.z += aB.z; s4.w += aB.w;
            q4.x += aB.x * aB.x; q4.y += aB.y * aB.y;
            q4.z += aB.z * aB.z; q4.w += aB.w * aB.w;
        }
    }
    atomicAdd(&ls[4 * l32 + 0], s4.x); atomicAdd(&ls[4 * l32 + 1], s4.y);
    atomicAdd(&ls[4 * l32 + 2], s4.z); atomicAdd(&ls[4 * l32 + 3], s4.w);
    atomicAdd(&lq[4 * l32 + 0], q4.x); atomicAdd(&lq[4 * l32 + 1], q4.y);
    atomicAdd(&lq[4 * l32 + 2], q4.z); atomicAdd(&lq[4 * l32 + 3], q4.w);
    __syncthreads();
    if (tid < D) {
        atomicAdd(&sums[tid], ls[tid]);
        atomicAdd(&sumsq[tid], lq[tid]);
    }
}

// ---------------- BN coefficient hoisting + apply ----------------
__global__ void bn_coef_kernel(const float* __restrict__ sums, const float* __restrict__ sumsq,
                               const float* __restrict__ gamma, const float* __restrict__ beta,
                               float* __restrict__ scale, float* __restrict__ shift, int nent) {
    int c = threadIdx.x;  // 128
    float inv_n = 1.0f / (float)nent;
    float mean = sums[c] * inv_n;
    float var = sumsq[c] * inv_n - mean * mean;
    float istd = rsqrtf(var + 1e-5f);
    float sc = istd * gamma[c];
    scale[c] = sc;
    shift[c] = beta[c] - mean * sc;
}

// bf16-h variant: read bf16 h, write f32 out; fused rel_embed passthrough
__global__ __launch_bounds__(256) void bn_apply2_bf_kernel(
        const unsigned short* __restrict__ h_bf, float* __restrict__ out,
        const float* __restrict__ scale, const float* __restrict__ shift,
        const float* __restrict__ rel_embed, float* __restrict__ pass, int nent, int npass4) {
    __shared__ float s_sc[D], s_sh[D];
    if (threadIdx.x < D) { s_sc[threadIdx.x] = scale[threadIdx.x]; s_sh[threadIdx.x] = shift[threadIdx.x]; }
    __syncthreads();
    long total = (long)nent * 32;   // uint2 units (4 elems each)
    long stride = (long)gridDim.x * blockDim.x;
    long idx0 = (long)blockIdx.x * blockDim.x + threadIdx.x;
    const uint2* hb2 = (const uint2*)h_bf;
    float4* out4 = (float4*)out;
    for (long i = idx0; i < total; i += stride) {
        int c0 = (int)((i & 31) << 2);
        uint2 v = hb2[i];
        float4 o;
        o.x = tanhf(__uint_as_float(v.x << 16)         * s_sc[c0 + 0] + s_sh[c0 + 0]);
        o.y = tanhf(__uint_as_float(v.x & 0xffff0000u) * s_sc[c0 + 1] + s_sh[c0 + 1]);
        o.z = tanhf(__uint_as_float(v.y << 16)         * s_sc[c0 + 2] + s_sh[c0 + 2]);
        o.w = tanhf(__uint_as_float(v.y & 0xffff0000u) * s_sc[c0 + 3] + s_sh[c0 + 3]);
        out4[i] = o;
    }
    const float4* re4 = (const float4*)rel_embed;
    float4* p4 = (float4*)pass;
    for (long i = idx0; i < npass4; i += stride) p4[i] = re4[i];
}

// f32 variant (when ws can't hold h_bf)
__global__ __launch_bounds__(256) void bn_apply2_kernel(
        float* __restrict__ h, const float* __restrict__ scale, const float* __restrict__ shift,
        const float* __restrict__ rel_embed, float* __restrict__ pass, int nent, int npass4) {
    __shared__ float s_sc[D], s_sh[D];
    if (threadIdx.x < D) { s_sc[threadIdx.x] = scale[threadIdx.x]; s_sh[threadIdx.x] = shift[threadIdx.x]; }
    __syncthreads();
    long total = (long)nent * (D / 4);
    long stride = (long)gridDim.x * blockDim.x;
    long idx0 = (long)blockIdx.x * blockDim.x + threadIdx.x;
    float4* h4 = (float4*)h;
    for (long i = idx0; i < total; i += stride) {
        int c0 = (int)((i & 31) << 2);
        float4 v = h4[i];
        v.x = tanhf(v.x * s_sc[c0 + 0] + s_sh[c0 + 0]);
        v.y = tanhf(v.y * s_sc[c0 + 1] + s_sh[c0 + 1]);
        v.z = tanhf(v.z * s_sc[c0 + 2] + s_sh[c0 + 2]);
        v.w = tanhf(v.w * s_sc[c0 + 3] + s_sh[c0 + 3]);
        h4[i] = v;
    }
    const float4* re4 = (const float4*)rel_embed;
    float4* p4 = (float4*)pass;
    for (long i = idx0; i < npass4; i += stride) p4[i] = re4[i];
}

// ---------------- fallback (atomic) path kernels ----------------
__global__ __launch_bounds__(256) void degree_kernel(const int* __restrict__ rows, int E,
                                                     float* __restrict__ deg_in,
                                                     float* __restrict__ deg_out) {
    int total = 2 * E;
    int tid = blockIdx.x * blockDim.x + threadIdx.x;
    int nth = gridDim.x * blockDim.x;
    for (long b = (long)tid * BUNROLL; b < total; b += (long)nth * BUNROLL) {
        for (int k = 0; k < BUNROLL && b + k < total; ++k) {
            int r = rows[b + k];
            float* deg = (b + k < E) ? deg_in : deg_out;
            atomicAdd(&deg[r], 1.0f);
        }
    }
}

__global__ void scatter_kernel(const int* __restrict__ rows, const int* __restrict__ cols,
                               const int* __restrict__ etype,
                               const float* __restrict__ deg_in, const float* __restrict__ deg_out,
                               const float* __restrict__ T_in, const float* __restrict__ T_out,
                               float* __restrict__ out, int E) {
    int wave = (blockIdx.x * blockDim.x + threadIdx.x) >> 6;
    int lane = threadIdx.x & 63;
    int nwaves = (gridDim.x * blockDim.x) >> 6;
    int total = 2 * E;
    for (int e = wave; e < total; e += nwaves) {
        bool first = (e < E);
        int row = rows[e];
        int col = cols[e];
        int t = etype[e];
        const float* deg = first ? deg_in : deg_out;
        const float* T = first ? T_in : T_out;
        float dr = deg[row];
        float dc = deg[col];
        float norm = (dr > 0.f ? rsqrtf(dr) : 0.f) * (dc > 0.f ? rsqrtf(dc) : 0.f);
        float c = 0.5f * norm;
        if (c != 0.f) {
            float v0 = c * T[t * D + lane];
            float v1 = c * T[t * D + 64 + lane];
            long b = (long)row * D;
            atomicAdd(&out[b + lane], v0);
            atomicAdd(&out[b + 64 + lane], v1);
        }
    }
}

__global__ void bn_stats_kernel(const float* __restrict__ h, int nent,
                                float* __restrict__ sums, float* __restrict__ sumsq) {
    int col = threadIdx.x;
    float s = 0.f, s2 = 0.f;
    for (int r = blockIdx.x; r < nent; r += gridDim.x) {
        float v = h[(long)r * D + col];
        s += v;
        s2 += v * v;
    }
    atomicAdd(&sums[col], s);
    atomicAdd(&sumsq[col], s2);
}

__global__ void bn_apply_kernel(float* __restrict__ h,
                                const float* __restrict__ sums, const float* __restrict__ sumsq,
                                const float* __restrict__ gamma, const float* __restrict__ beta,
                                int nent) {
    long total = ((long)nent * D) / 4;
    long stride = (long)gridDim.x * blockDim.x;
    float inv_n = 1.0f / (float)nent;
    float4* h4 = (float4*)h;
    for (long i = (long)blockIdx.x * blockDim.x + threadIdx.x; i < total; i += stride) {
        int c0 = (int)((i * 4) & (D - 1));
        float4 v = h4[i];
        float r[4] = {v.x, v.y, v.z, v.w};
#pragma unroll
        for (int j = 0; j < 4; ++j) {
            int col = c0 + j;
            float mean = sums[col] * inv_n;
            float var = sumsq[col] * inv_n - mean * mean;
            float istd = rsqrtf(var + 1e-5f);
            r[j] = tanhf((r[j] - mean) * istd * gamma[col] + beta[col]);
        }
        h4[i] = make_float4(r[0], r[1], r[2], r[3]);
    }
}

extern "C" void kernel_launch(void* const* d_in, const int* in_sizes, int n_in,
                              void* d_out, int out_size, void* d_ws, size_t ws_size,
                              hipStream_t stream) {
    const float* rel_embed     = (const float*)d_in[0];
    const float* rel_embed_in  = (const float*)d_in[1];
    const float* rel_embed_out = (const float*)d_in[2];
    const float* w_in          = (const float*)d_in[3];
    const float* w_out         = (const float*)d_in[4];
    const float* bn_gamma      = (const float*)d_in[5];
    const float* bn_beta       = (const float*)d_in[6];
    const int*   edge_index    = (const int*)d_in[7];
    const int*   edge_type     = (const int*)d_in[8];

    const int nrel = in_sizes[0] / D;               // 500
    const int E2   = in_sizes[8];                   // 3,000,000
    const int E    = E2 / 2;                        // 1,500,000
    const int nent = (out_size - in_sizes[0]) / D;  // 200,000
    const int K    = (nent + RPB - 1) / RPB;        // 1563 buckets
    const int NB   = (E2 + CHUNK4 - 1) / CHUNK4;    // 367 blocks
    const long NBK = (long)NB * K;                  // ~574K counters
    const int ntiles = (int)((NBK + STILE - 1) / STILE);  // ~561

    float* out = (float*)d_out;
    const int* rows = edge_index;
    const int* cols = edge_index + E2;

    // ---- workspace layout (fast path) ----
    float*          ws       = (float*)d_ws;
    float*          dinvAll  = ws;                                   // 2*nent
    float*          sums     = dinvAll + (size_t)2 * nent;           // D
    float*          sumsq    = sums + D;                             // D
    float*          scale    = sumsq + D;                            // D
    float*          shift    = scale + D;                            // D
    unsigned*       rowBase  = (unsigned*)(shift + D);               // K*RPB
    unsigned*       cnt      = rowBase + (size_t)K * RPB;            // NBK+1 (scan in place)
    unsigned*       tsum     = cnt + NBK + 1;                        // ntiles
    unsigned*       toff     = tsum + ntiles;                        // ntiles
    unsigned short* T_bf     = (unsigned short*)(toff + ntiles);     // 2*nrel*D bf16
    uintptr_t pal = ((uintptr_t)(T_bf + (size_t)2 * nrel * D) + 15) & ~(uintptr_t)15;
    uint2*          payload  = (uint2*)pal;                          // E2
    uintptr_t pal2 = ((uintptr_t)(payload + E2) + 15) & ~(uintptr_t)15;
    unsigned short* h_bf     = (unsigned short*)pal2;                // nent*D bf16 (optional)
    size_t needed    = pal2 - (uintptr_t)d_ws;
    size_t needed_bf = needed + (size_t)nent * D * sizeof(unsigned short);

    bool fast   = (needed <= ws_size) && (K <= MAXK) && (2 * nrel <= 1024) &&
                  (ntiles <= 1024);
    int  use_bf = fast && (needed_bf <= ws_size);

    if (fast) {
        hipMemsetAsync(sums, 0, (size_t)2 * D * sizeof(float), stream);

        transform2_bf_kernel<<<2 * nrel, D, 0, stream>>>(rel_embed_in, w_in,
                                                         rel_embed_out, w_out, T_bf, nrel);
        hist4_kernel<<<NB, 512, 0, stream>>>(rows, E2, cnt, NB, K);
        tile_sum_u32<<<ntiles, 256, 0, stream>>>(cnt, tsum, (int)NBK);
        scan_tiles_kernel<<<1, 1024, 0, stream>>>(tsum, toff, cnt, ntiles, (int)NBK);
        base_write_u32<<<ntiles, 256, 0, stream>>>(cnt, toff, cnt, (int)NBK);
        scatter4_kernel<<<NB, 512, 0, stream>>>(rows, cols, edge_type, cnt,
                                                payload, E, E2, nrel, NB, K);
        degsort_kernel<<<K, 512, 0, stream>>>(cnt, payload, dinvAll, rowBase,
                                              nent, nrel, NB, K);
        accum4_kernel<<<K, 512, 0, stream>>>(cnt, payload, T_bf, dinvAll, rowBase,
                                             out, h_bf, use_bf, sums, sumsq,
                                             nent, nrel, NB, K);
        bn_coef_kernel<<<1, D, 0, stream>>>(sums, sumsq, bn_gamma, bn_beta,
                                            scale, shift, nent);
        if (use_bf) {
            bn_apply2_bf_kernel<<<2048, 256, 0, stream>>>(h_bf, out, scale, shift, rel_embed,
                                                          out + (size_t)nent * D, nent,
                                                          (nrel * D) / 4);
        } else {
            bn_apply2_kernel<<<2048, 256, 0, stream>>>(out, scale, shift, rel_embed,
                                                       out + (size_t)nent * D, nent,
                                                       (nrel * D) / 4);
        }
    } else {
        // ---------- fallback atomic path (f32 everywhere) ----------
        float* f_deg_in  = ws;
        float* f_deg_out = f_deg_in + nent;
        float* f_T_in    = f_deg_out + nent;
        float* f_T_out   = f_T_in + (size_t)nrel * D;
        float* f_sums    = f_T_out + (size_t)nrel * D;
        float* f_sumsq   = f_sums + D;

        hipMemsetAsync(out, 0, (size_t)nent * D * sizeof(float), stream);
        hipMemsetAsync(f_deg_in, 0, (size_t)2 * nent * sizeof(float), stream);
        hipMemsetAsync(f_sums, 0, (size_t)2 * D * sizeof(float), stream);

        transform2_kernel<<<2 * nrel, D, 0, stream>>>(rel_embed_in, w_in, rel_embed_out, w_out,
                                                      f_T_in, nrel);
        degree_kernel<<<1466, 256, 0, stream>>>(edge_index, E, f_deg_in, f_deg_out);
        scatter_kernel<<<2048, 256, 0, stream>>>(rows, cols, edge_type, f_deg_in, f_deg_out,
                                                 f_T_in, f_T_out, out, E);
        bn_stats_kernel<<<1024, D, 0, stream>>>(out, nent, f_sums, f_sumsq);
        bn_apply_kernel<<<4096, 256, 0, stream>>>(out, f_sums, f_sumsq, bn_gamma, bn_beta, nent);
        hipMemcpyAsync(out + (size_t)nent * D, rel_embed,
                       (size_t)nrel * D * sizeof(float), hipMemcpyDeviceToDevice, stream);
    }
}

// Round 16
// 218.510 us; speedup vs baseline: 1.4778x; 1.0326x over previous
//
#include <hip/hip_runtime.h>

#define D 128
#define BUNROLL 8
#define RPB 128                 // rows per bucket
#define CAP 2560                // max edges sorted in LDS per bucket (avg ~1920)
#define MAXK 2048               // max buckets (LDS histogram size)
#define CHUNK4 8192             // edges per block in hist4/scatter4 (identical mapping!)
#define STILE 1024              // scan tile

__device__ __forceinline__ unsigned f2bf_rne(float x) {
    unsigned u = __float_as_uint(x);
    return (u + 0x7fffu + ((u >> 16) & 1u)) >> 16;
}

#define FMA4(a, c, t)                                        \
    (a).x += (c) * __uint_as_float((t).x << 16);             \
    (a).y += (c) * __uint_as_float((t).x & 0xffff0000u);     \
    (a).z += (c) * __uint_as_float((t).y << 16);             \
    (a).w += (c) * __uint_as_float((t).y & 0xffff0000u);

// ---------------- relation transform -> bf16 table (fast path) ----------------
__global__ void transform2_bf_kernel(const float* __restrict__ Rin, const float* __restrict__ Win,
                                     const float* __restrict__ Rout, const float* __restrict__ Wout,
                                     unsigned short* __restrict__ T_bf, int nrel) {
    __shared__ float row[D];
    int b = blockIdx.x;
    bool second = (b >= nrel);
    const float* R = second ? Rout : Rin;
    const float* W = second ? Wout : Win;
    int r = second ? b - nrel : b;
    int t = threadIdx.x;
    row[t] = R[r * D + t];
    __syncthreads();
    float acc = 0.f;
#pragma unroll 8
    for (int k = 0; k < D; ++k) acc += row[k] * W[k * D + t];
    T_bf[(size_t)b * D + t] = (unsigned short)f2bf_rne(acc);
}

// f32 version (fallback path)
__global__ void transform2_kernel(const float* __restrict__ Rin, const float* __restrict__ Win,
                                  const float* __restrict__ Rout, const float* __restrict__ Wout,
                                  float* __restrict__ T_all, int nrel) {
    __shared__ float row[D];
    int b = blockIdx.x;
    bool second = (b >= nrel);
    const float* R = second ? Rout : Rin;
    const float* W = second ? Wout : Win;
    int r = second ? b - nrel : b;
    int t = threadIdx.x;
    row[t] = R[r * D + t];
    __syncthreads();
    float acc = 0.f;
#pragma unroll 8
    for (int k = 0; k < D; ++k) acc += row[k] * W[k * D + t];
    T_all[(size_t)b * D + t] = acc;
}

// ---------------- pass 1: per-block LDS bucket histogram (int4 loads) ----------------
__global__ __launch_bounds__(512) void hist4_kernel(
        const int* __restrict__ rows, int E2,
        unsigned* __restrict__ cnt, int NB, int K) {
    __shared__ unsigned h[MAXK];
    int tid = threadIdx.x, blk = blockIdx.x;
    for (int i = tid; i < K; i += 512) h[i] = 0;
    __syncthreads();
    long s = (long)blk * CHUNK4;
    long e = s + CHUNK4; if (e > E2) e = E2;
    long n = e - s;
    if ((n & 3) == 0) {
        const int4* r4 = (const int4*)(rows + s);
        int m = (int)(n >> 2);
        for (int i = tid; i < m; i += 512) {
            int4 r = r4[i];
            atomicAdd(&h[((unsigned)r.x) >> 7], 1u);
            atomicAdd(&h[((unsigned)r.y) >> 7], 1u);
            atomicAdd(&h[((unsigned)r.z) >> 7], 1u);
            atomicAdd(&h[((unsigned)r.w) >> 7], 1u);
        }
    } else {
        for (long i = s + tid; i < e; i += 512)
            atomicAdd(&h[((unsigned)rows[i]) >> 7], 1u);
    }
    __syncthreads();
    for (int i = tid; i < K; i += 512)
        cnt[(size_t)i * NB + blk] = h[i];
}

// ---------------- device-wide scan over n=NB*K counters ----------------
__global__ __launch_bounds__(256) void tile_sum_u32(const unsigned int* __restrict__ cnt,
                                                    unsigned int* __restrict__ tsum, int n) {
    int tid = threadIdx.x;
    int i0 = blockIdx.x * STILE + tid * 4;
    unsigned int s = 0;
#pragma unroll
    for (int k = 0; k < 4; ++k) {
        int i = i0 + k;
        if (i < n) s += cnt[i];
    }
    __shared__ unsigned int ls[256];
    ls[tid] = s;
    __syncthreads();
    for (int off = 128; off >= 1; off >>= 1) {
        if (tid < off) ls[tid] += ls[tid + off];
        __syncthreads();
    }
    if (tid == 0) tsum[blockIdx.x] = ls[0];
}

__global__ void scan_tiles_kernel(const unsigned int* __restrict__ tile_sums,
                                  unsigned int* __restrict__ tile_off,
                                  unsigned int* __restrict__ base, int ntiles, int n) {
    int t = threadIdx.x; // blockDim = 1024
    __shared__ unsigned int ls[1024];
    unsigned int v = (t < ntiles) ? tile_sums[t] : 0u;
    ls[t] = v;
    __syncthreads();
    for (int off = 1; off < 1024; off <<= 1) {
        unsigned int add = (t >= off) ? ls[t - off] : 0u;
        __syncthreads();
        ls[t] += add;
        __syncthreads();
    }
    if (t < ntiles) tile_off[t] = ls[t] - v; // exclusive
    if (t == 1023) base[n] = ls[1023];       // grand total
}

// in-place safe when base==cnt
__global__ __launch_bounds__(256) void base_write_u32(const unsigned int* __restrict__ cnt,
                                                      const unsigned int* __restrict__ tile_off,
                                                      unsigned int* __restrict__ base, int n) {
    int tid = threadIdx.x;
    int i0 = blockIdx.x * STILE + tid * 4;
    unsigned int c[4];
#pragma unroll
    for (int k = 0; k < 4; ++k) {
        int i = i0 + k;
        c[k] = (i < n) ? cnt[i] : 0u;
    }
    unsigned int s = c[0] + c[1] + c[2] + c[3];
    __shared__ unsigned int ls[256];
    ls[tid] = s;
    __syncthreads();
    for (int off = 1; off < 256; off <<= 1) {
        unsigned int add = (tid >= off) ? ls[tid - off] : 0u;
        __syncthreads();
        ls[tid] += add;
        __syncthreads();
    }
    unsigned int run = (tid > 0 ? ls[tid - 1] : 0u) + tile_off[blockIdx.x];
#pragma unroll
    for (int k = 0; k < 4; ++k) {
        int i = i0 + k;
        if (i < n) base[i] = run;
        run += c[k];
    }
}

// ---------------- pass 2: scatter with LDS ranks (int4 loads) ----------------
// payload = (col, (row&127)<<10 | type)
__global__ __launch_bounds__(512) void scatter4_kernel(
        const int* __restrict__ rows, const int* __restrict__ cols,
        const int* __restrict__ etype, const unsigned* __restrict__ base,
        uint2* __restrict__ payload, int E, int E2, int nrel, int NB, int K) {
    __shared__ unsigned cur[MAXK];
    int tid = threadIdx.x, blk = blockIdx.x;
    for (int i = tid; i < K; i += 512) cur[i] = base[(size_t)i * NB + blk];
    __syncthreads();
    long s = (long)blk * CHUNK4;
    long e = s + CHUNK4; if (e > E2) e = E2;
    long n = e - s;
    if ((n & 3) == 0) {
        const int4* r4 = (const int4*)(rows + s);
        const int4* c4 = (const int4*)(cols + s);
        const int4* t4 = (const int4*)(etype + s);
        int m = (int)(n >> 2);
        for (int i = tid; i < m; i += 512) {
            int4 r = r4[i];
            int4 c = c4[i];
            int4 t = t4[i];
            long e0 = s + ((long)i << 2);
            unsigned pos, ty;
            ty = (unsigned)t.x + ((e0 + 0 < E) ? 0u : (unsigned)nrel);
            pos = atomicAdd(&cur[((unsigned)r.x) >> 7], 1u);
            payload[pos] = make_uint2((unsigned)c.x, (((unsigned)r.x & 127u) << 10) | ty);
            ty = (unsigned)t.y + ((e0 + 1 < E) ? 0u : (unsigned)nrel);
            pos = atomicAdd(&cur[((unsigned)r.y) >> 7], 1u);
            payload[pos] = make_uint2((unsigned)c.y, (((unsigned)r.y & 127u) << 10) | ty);
            ty = (unsigned)t.z + ((e0 + 2 < E) ? 0u : (unsigned)nrel);
            pos = atomicAdd(&cur[((unsigned)r.z) >> 7], 1u);
            payload[pos] = make_uint2((unsigned)c.z, (((unsigned)r.z & 127u) << 10) | ty);
            ty = (unsigned)t.w + ((e0 + 3 < E) ? 0u : (unsigned)nrel);
            pos = atomicAdd(&cur[((unsigned)r.w) >> 7], 1u);
            payload[pos] = make_uint2((unsigned)c.w, (((unsigned)r.w & 127u) << 10) | ty);
        }
    } else {
        for (long i = s + tid; i < e; i += 512) {
            unsigned r = (unsigned)rows[i];
            unsigned c = (unsigned)cols[i];
            unsigned t = (unsigned)etype[i];
            unsigned ty = t + ((i < E) ? 0u : (unsigned)nrel);
            unsigned pos = atomicAdd(&cur[r >> 7], 1u);
            payload[pos] = make_uint2(c, ((r & 127u) << 10) | ty);
        }
    }
}

// ---------------- degrees + per-bucket row offsets from sorted payload ----------------
__global__ __launch_bounds__(512) void degsort_kernel(
        const unsigned* __restrict__ base, const uint2* __restrict__ payload,
        float* __restrict__ dinvAll, unsigned* __restrict__ rowBase,
        int nent, int nrel, int NB, int K) {
    __shared__ unsigned h2[RPB * 2];
    __shared__ unsigned sc[RPB];
    int tid = threadIdx.x, b = blockIdx.x;
    if (tid < RPB * 2) h2[tid] = 0;
    __syncthreads();
    size_t NBK = (size_t)NB * K;
    unsigned s = base[(size_t)b * NB];
    unsigned e = (b + 1 < K) ? base[(size_t)(b + 1) * NB] : base[NBK];
    for (unsigned i = s + tid; i < e; i += 512) {
        unsigned y = payload[i].y;
        unsigned lr = (y >> 10) & 127u;
        unsigned fo = ((y & 1023u) >= (unsigned)nrel) ? 1u : 0u;
        atomicAdd(&h2[lr * 2 + fo], 1u);
    }
    __syncthreads();
    unsigned tot = 0;
    if (tid < RPB) { tot = h2[tid * 2] + h2[tid * 2 + 1]; sc[tid] = tot; }
    __syncthreads();
    for (int off = 1; off < RPB; off <<= 1) {
        unsigned v = 0;
        if (tid < RPB && tid >= off) v = sc[tid - off];
        __syncthreads();
        if (tid < RPB) sc[tid] += v;
        __syncthreads();
    }
    if (tid < RPB) {
        rowBase[(size_t)b * RPB + tid] = sc[tid] - tot;   // exclusive prefix
        int row = (b << 7) + tid;
        if (row < nent) {
            unsigned a = h2[tid * 2], o = h2[tid * 2 + 1];
            dinvAll[row]        = a ? rsqrtf((float)a) : 0.f;
            dinvAll[nent + row] = o ? rsqrtf((float)o) : 0.f;
        }
    }
}

// ---------------- per-bucket reorder + register accumulate (R14 single-row form) ----------
__global__ __launch_bounds__(512) void accum4_kernel(
        const unsigned* __restrict__ base, const uint2* __restrict__ payload,
        const unsigned short* __restrict__ T_bf, const float* __restrict__ dinvAll,
        const unsigned* __restrict__ rowBase,
        float* __restrict__ out, unsigned short* __restrict__ h_bf, int use_bf,
        float* __restrict__ sums, float* __restrict__ sumsq,
        int nent, int nrel, int NB, int K) {
    __shared__ uint2 sp[CAP];              // 20 KB
    __shared__ unsigned hstart[RPB];
    __shared__ unsigned hcur[RPB];
    __shared__ float ls[D], lq[D];
    int tid = threadIdx.x;
    int b = blockIdx.x;
    size_t NBK = (size_t)NB * K;
    unsigned start = base[(size_t)b * NB];
    unsigned end   = (b + 1 < K) ? base[(size_t)(b + 1) * NB] : base[NBK];
    int n = (int)(end - start);
    int nin = n < CAP ? n : CAP;

    if (tid < RPB) { ls[tid] = 0.f; lq[tid] = 0.f; }

    if (n <= CAP) {
        if (tid < RPB) {
            unsigned v = rowBase[(size_t)b * RPB + tid];
            hstart[tid] = v;
            hcur[tid] = v;
        }
        __syncthreads();
        for (int i = tid; i < nin; i += 512) {
            uint2 p = payload[start + i];
            unsigned pos = atomicAdd(&hcur[(p.y >> 10) & 127u], 1u);
            sp[pos] = p;
        }
        __syncthreads();
    } else {
        if (tid < RPB) hstart[tid] = 0;
        __syncthreads();
        for (int i = tid; i < nin; i += 512)
            atomicAdd(&hstart[(payload[start + i].y >> 10) & 127u], 1u);
        __syncthreads();
        for (int off = 1; off < RPB; off <<= 1) {
            unsigned v = 0;
            if (tid < RPB && tid >= off) v = hstart[tid - off];
            __syncthreads();
            if (tid < RPB) hstart[tid] += v;
            __syncthreads();
        }
        unsigned ex = 0;
        if (tid < RPB) ex = tid ? hstart[tid - 1] : 0u;
        __syncthreads();
        if (tid < RPB) { hstart[tid] = ex; hcur[tid] = ex; }
        __syncthreads();
        for (int i = tid; i < nin; i += 512) {
            uint2 p = payload[start + i];
            unsigned pos = atomicAdd(&hcur[(p.y >> 10) & 127u], 1u);
            sp[pos] = p;
        }
        __syncthreads();
    }

    const uint2* T2 = (const uint2*)T_bf;   // one row = 128 bf16 = 32 uint2
    float4* out4 = (float4*)out;
    uint2* hb2 = (uint2*)h_bf;
    int hw = tid >> 5, l32 = tid & 31;
    int row0 = b << 7;
    unsigned unrel = (unsigned)nrel;
    float4 s4 = make_float4(0.f, 0.f, 0.f, 0.f);
    float4 q4 = make_float4(0.f, 0.f, 0.f, 0.f);
    for (int rr = 0; rr < 8; ++rr) {
        int r = (hw << 3) + rr;
        int row = row0 + r;
        float da_in = 0.f, da_out = 0.f;
        if (row < nent) { da_in = dinvAll[row]; da_out = dinvAll[nent + row]; }
        unsigned s0 = hstart[r];
        unsigned s1 = (r < RPB - 1) ? hstart[r + 1] : (unsigned)nin;
        float4 a = make_float4(0.f, 0.f, 0.f, 0.f);
        unsigned i = s0;
        for (; i + 4 <= s1; i += 4) {      // 4-deep independent chains
            uint2 p0 = sp[i], p1 = sp[i + 1], p2 = sp[i + 2], p3 = sp[i + 3];
            unsigned ty0 = p0.y & 1023u, ty1 = p1.y & 1023u;
            unsigned ty2 = p2.y & 1023u, ty3 = p3.y & 1023u;
            bool f0 = ty0 < unrel, f1 = ty1 < unrel, f2 = ty2 < unrel, f3 = ty3 < unrel;
            float dc0 = dinvAll[(f0 ? 0 : nent) + p0.x];
            float dc1 = dinvAll[(f1 ? 0 : nent) + p1.x];
            float dc2 = dinvAll[(f2 ? 0 : nent) + p2.x];
            float dc3 = dinvAll[(f3 ? 0 : nent) + p3.x];
            uint2 t0 = T2[(size_t)ty0 * 32 + l32];
            uint2 t1 = T2[(size_t)ty1 * 32 + l32];
            uint2 t2 = T2[(size_t)ty2 * 32 + l32];
            uint2 t3 = T2[(size_t)ty3 * 32 + l32];
            float c0 = 0.5f * (f0 ? da_in : da_out) * dc0;
            float c1 = 0.5f * (f1 ? da_in : da_out) * dc1;
            float c2 = 0.5f * (f2 ? da_in : da_out) * dc2;
            float c3 = 0.5f * (f3 ? da_in : da_out) * dc3;
            FMA4(a, c0, t0) FMA4(a, c1, t1) FMA4(a, c2, t2) FMA4(a, c3, t3)
        }
        for (; i < s1; ++i) {
            uint2 p = sp[i];
            unsigned ty = p.y & 1023u;
            bool f = ty < unrel;
            float c = 0.5f * (f ? da_in : da_out) * dinvAll[(f ? 0 : nent) + p.x];
            uint2 t = T2[(size_t)ty * 32 + l32];
            FMA4(a, c, t)
        }
        // overflow tail (n > CAP): correctness fallback
        for (unsigned j = start + (unsigned)nin; j < end; ++j) {
            uint2 p = payload[j];
            if (((p.y >> 10) & 127u) == (unsigned)r) {
                unsigned ty = p.y & 1023u;
                bool f = ty < unrel;
                float c = 0.5f * (f ? da_in : da_out) * dinvAll[(f ? 0 : nent) + p.x];
                uint2 t = T2[(size_t)ty * 32 + l32];
                FMA4(a, c, t)
            }
        }
        if (row < nent) {
            if (use_bf) {
                hb2[(size_t)row * 32 + l32] = make_uint2(
                    f2bf_rne(a.x) | (f2bf_rne(a.y) << 16),
                    f2bf_rne(a.z) | (f2bf_rne(a.w) << 16));
            } else {
                out4[(size_t)row * 32 + l32] = a;
            }
            s4.x += a.x; s4.y += a.y; s4.z += a.z; s4.w += a.w;
            q4.x += a.x * a.x; q4.y += a.y * a.y; q4.z += a.z * a.z; q4.w += a.w * a.w;
        }
    }
    atomicAdd(&ls[4 * l32 + 0], s4.x); atomicAdd(&ls[4 * l32 + 1], s4.y);
    atomicAdd(&ls[4 * l32 + 2], s4.z); atomicAdd(&ls[4 * l32 + 3], s4.w);
    atomicAdd(&lq[4 * l32 + 0], q4.x); atomicAdd(&lq[4 * l32 + 1], q4.y);
    atomicAdd(&lq[4 * l32 + 2], q4.z); atomicAdd(&lq[4 * l32 + 3], q4.w);
    __syncthreads();
    if (tid < D) {
        atomicAdd(&sums[tid], ls[tid]);
        atomicAdd(&sumsq[tid], lq[tid]);
    }
}

// ---------------- BN coefficient hoisting + apply ----------------
__global__ void bn_coef_kernel(const float* __restrict__ sums, const float* __restrict__ sumsq,
                               const float* __restrict__ gamma, const float* __restrict__ beta,
                               float* __restrict__ scale, float* __restrict__ shift, int nent) {
    int c = threadIdx.x;  // 128
    float inv_n = 1.0f / (float)nent;
    float mean = sums[c] * inv_n;
    float var = sumsq[c] * inv_n - mean * mean;
    float istd = rsqrtf(var + 1e-5f);
    float sc = istd * gamma[c];
    scale[c] = sc;
    shift[c] = beta[c] - mean * sc;
}

// bf16-h variant: read bf16 h, write f32 out; fused rel_embed passthrough
__global__ __launch_bounds__(256) void bn_apply2_bf_kernel(
        const unsigned short* __restrict__ h_bf, float* __restrict__ out,
        const float* __restrict__ scale, const float* __restrict__ shift,
        const float* __restrict__ rel_embed, float* __restrict__ pass, int nent, int npass4) {
    __shared__ float s_sc[D], s_sh[D];
    if (threadIdx.x < D) { s_sc[threadIdx.x] = scale[threadIdx.x]; s_sh[threadIdx.x] = shift[threadIdx.x]; }
    __syncthreads();
    long total = (long)nent * 32;   // uint2 units (4 elems each)
    long stride = (long)gridDim.x * blockDim.x;
    long idx0 = (long)blockIdx.x * blockDim.x + threadIdx.x;
    const uint2* hb2 = (const uint2*)h_bf;
    float4* out4 = (float4*)out;
    for (long i = idx0; i < total; i += stride) {
        int c0 = (int)((i & 31) << 2);
        uint2 v = hb2[i];
        float4 o;
        o.x = tanhf(__uint_as_float(v.x << 16)         * s_sc[c0 + 0] + s_sh[c0 + 0]);
        o.y = tanhf(__uint_as_float(v.x & 0xffff0000u) * s_sc[c0 + 1] + s_sh[c0 + 1]);
        o.z = tanhf(__uint_as_float(v.y << 16)         * s_sc[c0 + 2] + s_sh[c0 + 2]);
        o.w = tanhf(__uint_as_float(v.y & 0xffff0000u) * s_sc[c0 + 3] + s_sh[c0 + 3]);
        out4[i] = o;
    }
    const float4* re4 = (const float4*)rel_embed;
    float4* p4 = (float4*)pass;
    for (long i = idx0; i < npass4; i += stride) p4[i] = re4[i];
}

// f32 variant (when ws can't hold h_bf)
__global__ __launch_bounds__(256) void bn_apply2_kernel(
        float* __restrict__ h, const float* __restrict__ scale, const float* __restrict__ shift,
        const float* __restrict__ rel_embed, float* __restrict__ pass, int nent, int npass4) {
    __shared__ float s_sc[D], s_sh[D];
    if (threadIdx.x < D) { s_sc[threadIdx.x] = scale[threadIdx.x]; s_sh[threadIdx.x] = shift[threadIdx.x]; }
    __syncthreads();
    long total = (long)nent * (D / 4);
    long stride = (long)gridDim.x * blockDim.x;
    long idx0 = (long)blockIdx.x * blockDim.x + threadIdx.x;
    float4* h4 = (float4*)h;
    for (long i = idx0; i < total; i += stride) {
        int c0 = (int)((i & 31) << 2);
        float4 v = h4[i];
        v.x = tanhf(v.x * s_sc[c0 + 0] + s_sh[c0 + 0]);
        v.y = tanhf(v.y * s_sc[c0 + 1] + s_sh[c0 + 1]);
        v.z = tanhf(v.z * s_sc[c0 + 2] + s_sh[c0 + 2]);
        v.w = tanhf(v.w * s_sc[c0 + 3] + s_sh[c0 + 3]);
        h4[i] = v;
    }
    const float4* re4 = (const float4*)rel_embed;
    float4* p4 = (float4*)pass;
    for (long i = idx0; i < npass4; i += stride) p4[i] = re4[i];
}

// ---------------- fallback (atomic) path kernels ----------------
__global__ __launch_bounds__(256) void degree_kernel(const int* __restrict__ rows, int E,
                                                     float* __restrict__ deg_in,
                                                     float* __restrict__ deg_out) {
    int total = 2 * E;
    int tid = blockIdx.x * blockDim.x + threadIdx.x;
    int nth = gridDim.x * blockDim.x;
    for (long b = (long)tid * BUNROLL; b < total; b += (long)nth * BUNROLL) {
        for (int k = 0; k < BUNROLL && b + k < total; ++k) {
            int r = rows[b + k];
            float* deg = (b + k < E) ? deg_in : deg_out;
            atomicAdd(&deg[r], 1.0f);
        }
    }
}

__global__ void scatter_kernel(const int* __restrict__ rows, const int* __restrict__ cols,
                               const int* __restrict__ etype,
                               const float* __restrict__ deg_in, const float* __restrict__ deg_out,
                               const float* __restrict__ T_in, const float* __restrict__ T_out,
                               float* __restrict__ out, int E) {
    int wave = (blockIdx.x * blockDim.x + threadIdx.x) >> 6;
    int lane = threadIdx.x & 63;
    int nwaves = (gridDim.x * blockDim.x) >> 6;
    int total = 2 * E;
    for (int e = wave; e < total; e += nwaves) {
        bool first = (e < E);
        int row = rows[e];
        int col = cols[e];
        int t = etype[e];
        const float* deg = first ? deg_in : deg_out;
        const float* T = first ? T_in : T_out;
        float dr = deg[row];
        float dc = deg[col];
        float norm = (dr > 0.f ? rsqrtf(dr) : 0.f) * (dc > 0.f ? rsqrtf(dc) : 0.f);
        float c = 0.5f * norm;
        if (c != 0.f) {
            float v0 = c * T[t * D + lane];
            float v1 = c * T[t * D + 64 + lane];
            long b = (long)row * D;
            atomicAdd(&out[b + lane], v0);
            atomicAdd(&out[b + 64 + lane], v1);
        }
    }
}

__global__ void bn_stats_kernel(const float* __restrict__ h, int nent,
                                float* __restrict__ sums, float* __restrict__ sumsq) {
    int col = threadIdx.x;
    float s = 0.f, s2 = 0.f;
    for (int r = blockIdx.x; r < nent; r += gridDim.x) {
        float v = h[(long)r * D + col];
        s += v;
        s2 += v * v;
    }
    atomicAdd(&sums[col], s);
    atomicAdd(&sumsq[col], s2);
}

__global__ void bn_apply_kernel(float* __restrict__ h,
                                const float* __restrict__ sums, const float* __restrict__ sumsq,
                                const float* __restrict__ gamma, const float* __restrict__ beta,
                                int nent) {
    long total = ((long)nent * D) / 4;
    long stride = (long)gridDim.x * blockDim.x;
    float inv_n = 1.0f / (float)nent;
    float4* h4 = (float4*)h;
    for (long i = (long)blockIdx.x * blockDim.x + threadIdx.x; i < total; i += stride) {
        int c0 = (int)((i * 4) & (D - 1));
        float4 v = h4[i];
        float r[4] = {v.x, v.y, v.z, v.w};
#pragma unroll
        for (int j = 0; j < 4; ++j) {
            int col = c0 + j;
            float mean = sums[col] * inv_n;
            float var = sumsq[col] * inv_n - mean * mean;
            float istd = rsqrtf(var + 1e-5f);
            r[j] = tanhf((r[j] - mean) * istd * gamma[col] + beta[col]);
        }
        h4[i] = make_float4(r[0], r[1], r[2], r[3]);
    }
}

extern "C" void kernel_launch(void* const* d_in, const int* in_sizes, int n_in,
                              void* d_out, int out_size, void* d_ws, size_t ws_size,
                              hipStream_t stream) {
    const float* rel_embed     = (const float*)d_in[0];
    const float* rel_embed_in  = (const float*)d_in[1];
    const float* rel_embed_out = (const float*)d_in[2];
    const float* w_in          = (const float*)d_in[3];
    const float* w_out         = (const float*)d_in[4];
    const float* bn_gamma      = (const float*)d_in[5];
    const float* bn_beta       = (const float*)d_in[6];
    const int*   edge_index    = (const int*)d_in[7];
    const int*   edge_type     = (const int*)d_in[8];

    const int nrel = in_sizes[0] / D;               // 500
    const int E2   = in_sizes[8];                   // 3,000,000
    const int E    = E2 / 2;                        // 1,500,000
    const int nent = (out_size - in_sizes[0]) / D;  // 200,000
    const int K    = (nent + RPB - 1) / RPB;        // 1563 buckets
    const int NB   = (E2 + CHUNK4 - 1) / CHUNK4;    // 367 blocks
    const long NBK = (long)NB * K;                  // ~574K counters
    const int ntiles = (int)((NBK + STILE - 1) / STILE);  // ~561

    float* out = (float*)d_out;
    const int* rows = edge_index;
    const int* cols = edge_index + E2;

    // ---- workspace layout (fast path) ----
    float*          ws       = (float*)d_ws;
    float*          dinvAll  = ws;                                   // 2*nent
    float*          sums     = dinvAll + (size_t)2 * nent;           // D
    float*          sumsq    = sums + D;                             // D
    float*          scale    = sumsq + D;                            // D
    float*          shift    = scale + D;                            // D
    unsigned*       rowBase  = (unsigned*)(shift + D);               // K*RPB
    unsigned*       cnt      = rowBase + (size_t)K * RPB;            // NBK+1 (scan in place)
    unsigned*       tsum     = cnt + NBK + 1;                        // ntiles
    unsigned*       toff     = tsum + ntiles;                        // ntiles
    unsigned short* T_bf     = (unsigned short*)(toff + ntiles);     // 2*nrel*D bf16
    uintptr_t pal = ((uintptr_t)(T_bf + (size_t)2 * nrel * D) + 15) & ~(uintptr_t)15;
    uint2*          payload  = (uint2*)pal;                          // E2
    uintptr_t pal2 = ((uintptr_t)(payload + E2) + 15) & ~(uintptr_t)15;
    unsigned short* h_bf     = (unsigned short*)pal2;                // nent*D bf16 (optional)
    size_t needed    = pal2 - (uintptr_t)d_ws;
    size_t needed_bf = needed + (size_t)nent * D * sizeof(unsigned short);

    bool fast   = (needed <= ws_size) && (K <= MAXK) && (2 * nrel <= 1024) &&
                  (ntiles <= 1024);
    int  use_bf = fast && (needed_bf <= ws_size);

    if (fast) {
        hipMemsetAsync(sums, 0, (size_t)2 * D * sizeof(float), stream);

        transform2_bf_kernel<<<2 * nrel, D, 0, stream>>>(rel_embed_in, w_in,
                                                         rel_embed_out, w_out, T_bf, nrel);
        hist4_kernel<<<NB, 512, 0, stream>>>(rows, E2, cnt, NB, K);
        tile_sum_u32<<<ntiles, 256, 0, stream>>>(cnt, tsum, (int)NBK);
        scan_tiles_kernel<<<1, 1024, 0, stream>>>(tsum, toff, cnt, ntiles, (int)NBK);
        base_write_u32<<<ntiles, 256, 0, stream>>>(cnt, toff, cnt, (int)NBK);
        scatter4_kernel<<<NB, 512, 0, stream>>>(rows, cols, edge_type, cnt,
                                                payload, E, E2, nrel, NB, K);
        degsort_kernel<<<K, 512, 0, stream>>>(cnt, payload, dinvAll, rowBase,
                                              nent, nrel, NB, K);
        accum4_kernel<<<K, 512, 0, stream>>>(cnt, payload, T_bf, dinvAll, rowBase,
                                             out, h_bf, use_bf, sums, sumsq,
                                             nent, nrel, NB, K);
        bn_coef_kernel<<<1, D, 0, stream>>>(sums, sumsq, bn_gamma, bn_beta,
                                            scale, shift, nent);
        if (use_bf) {
            bn_apply2_bf_kernel<<<2048, 256, 0, stream>>>(h_bf, out, scale, shift, rel_embed,
                                                          out + (size_t)nent * D, nent,
                                                          (nrel * D) / 4);
        } else {
            bn_apply2_kernel<<<2048, 256, 0, stream>>>(out, scale, shift, rel_embed,
                                                       out + (size_t)nent * D, nent,
                                                       (nrel * D) / 4);
        }
    } else {
        // ---------- fallback atomic path (f32 everywhere) ----------
        float* f_deg_in  = ws;
        float* f_deg_out = f_deg_in + nent;
        float* f_T_in    = f_deg_out + nent;
        float* f_T_out   = f_T_in + (size_t)nrel * D;
        float* f_sums    = f_T_out + (size_t)nrel * D;
        float* f_sumsq   = f_sums + D;

        hipMemsetAsync(out, 0, (size_t)nent * D * sizeof(float), stream);
        hipMemsetAsync(f_deg_in, 0, (size_t)2 * nent * sizeof(float), stream);
        hipMemsetAsync(f_sums, 0, (size_t)2 * D * sizeof(float), stream);

        transform2_kernel<<<2 * nrel, D, 0, stream>>>(rel_embed_in, w_in, rel_embed_out, w_out,
                                                      f_T_in, nrel);
        degree_kernel<<<1466, 256, 0, stream>>>(edge_index, E, f_deg_in, f_deg_out);
        scatter_kernel<<<2048, 256, 0, stream>>>(rows, cols, edge_type, f_deg_in, f_deg_out,
                                                 f_T_in, f_T_out, out, E);
        bn_stats_kernel<<<1024, D, 0, stream>>>(out, nent, f_sums, f_sumsq);
        bn_apply_kernel<<<4096, 256, 0, stream>>>(out, f_sums, f_sumsq, bn_gamma, bn_beta, nent);
        hipMemcpyAsync(out + (size_t)nent * D, rel_embed,
                       (size_t)nrel * D * sizeof(float), hipMemcpyDeviceToDevice, stream);
    }
}

// Round 17
// 205.291 us; speedup vs baseline: 1.5730x; 1.0644x over previous
//
#include <hip/hip_runtime.h>

#define D 128
#define BUNROLL 8
#define RPB 128                 // rows per bucket
#define CAP 2560                // max edges sorted in LDS per bucket (avg ~1920)
#define MAXK 2048               // max buckets (LDS histogram size)
#define CHUNK4 16384            // edges per block in hist4/scatter4 (identical mapping!)
#define STILE 1024              // scan tile

__device__ __forceinline__ unsigned f2bf_rne(float x) {
    unsigned u = __float_as_uint(x);
    return (u + 0x7fffu + ((u >> 16) & 1u)) >> 16;
}

#define FMA4(a, c, t)                                        \
    (a).x += (c) * __uint_as_float((t).x << 16);             \
    (a).y += (c) * __uint_as_float((t).x & 0xffff0000u);     \
    (a).z += (c) * __uint_as_float((t).y << 16);             \
    (a).w += (c) * __uint_as_float((t).y & 0xffff0000u);

// ---------------- relation transform -> bf16 table (fast path) ----------------
__global__ void transform2_bf_kernel(const float* __restrict__ Rin, const float* __restrict__ Win,
                                     const float* __restrict__ Rout, const float* __restrict__ Wout,
                                     unsigned short* __restrict__ T_bf, int nrel) {
    __shared__ float row[D];
    int b = blockIdx.x;
    bool second = (b >= nrel);
    const float* R = second ? Rout : Rin;
    const float* W = second ? Wout : Win;
    int r = second ? b - nrel : b;
    int t = threadIdx.x;
    row[t] = R[r * D + t];
    __syncthreads();
    float acc = 0.f;
#pragma unroll 8
    for (int k = 0; k < D; ++k) acc += row[k] * W[k * D + t];
    T_bf[(size_t)b * D + t] = (unsigned short)f2bf_rne(acc);
}

// f32 version (fallback path)
__global__ void transform2_kernel(const float* __restrict__ Rin, const float* __restrict__ Win,
                                  const float* __restrict__ Rout, const float* __restrict__ Wout,
                                  float* __restrict__ T_all, int nrel) {
    __shared__ float row[D];
    int b = blockIdx.x;
    bool second = (b >= nrel);
    const float* R = second ? Rout : Rin;
    const float* W = second ? Wout : Win;
    int r = second ? b - nrel : b;
    int t = threadIdx.x;
    row[t] = R[r * D + t];
    __syncthreads();
    float acc = 0.f;
#pragma unroll 8
    for (int k = 0; k < D; ++k) acc += row[k] * W[k * D + t];
    T_all[(size_t)b * D + t] = acc;
}

// ---------------- pass 1: per-block LDS bucket histogram (int4 loads) ----------------
__global__ __launch_bounds__(512) void hist4_kernel(
        const int* __restrict__ rows, int E2,
        unsigned* __restrict__ cnt, int NB, int K) {
    __shared__ unsigned h[MAXK];
    int tid = threadIdx.x, blk = blockIdx.x;
    for (int i = tid; i < K; i += 512) h[i] = 0;
    __syncthreads();
    long s = (long)blk * CHUNK4;
    long e = s + CHUNK4; if (e > E2) e = E2;
    long n = e - s;
    if ((n & 3) == 0) {
        const int4* r4 = (const int4*)(rows + s);
        int m = (int)(n >> 2);
        for (int i = tid; i < m; i += 512) {
            int4 r = r4[i];
            atomicAdd(&h[((unsigned)r.x) >> 7], 1u);
            atomicAdd(&h[((unsigned)r.y) >> 7], 1u);
            atomicAdd(&h[((unsigned)r.z) >> 7], 1u);
            atomicAdd(&h[((unsigned)r.w) >> 7], 1u);
        }
    } else {
        for (long i = s + tid; i < e; i += 512)
            atomicAdd(&h[((unsigned)rows[i]) >> 7], 1u);
    }
    __syncthreads();
    for (int i = tid; i < K; i += 512)
        cnt[(size_t)i * NB + blk] = h[i];
}

// ---------------- device-wide scan over n=NB*K counters ----------------
__global__ __launch_bounds__(256) void tile_sum_u32(const unsigned int* __restrict__ cnt,
                                                    unsigned int* __restrict__ tsum, int n) {
    int tid = threadIdx.x;
    int i0 = blockIdx.x * STILE + tid * 4;
    unsigned int s = 0;
#pragma unroll
    for (int k = 0; k < 4; ++k) {
        int i = i0 + k;
        if (i < n) s += cnt[i];
    }
    __shared__ unsigned int ls[256];
    ls[tid] = s;
    __syncthreads();
    for (int off = 128; off >= 1; off >>= 1) {
        if (tid < off) ls[tid] += ls[tid + off];
        __syncthreads();
    }
    if (tid == 0) tsum[blockIdx.x] = ls[0];
}

__global__ void scan_tiles_kernel(const unsigned int* __restrict__ tile_sums,
                                  unsigned int* __restrict__ tile_off,
                                  unsigned int* __restrict__ base, int ntiles, int n) {
    int t = threadIdx.x; // blockDim = 1024
    __shared__ unsigned int ls[1024];
    unsigned int v = (t < ntiles) ? tile_sums[t] : 0u;
    ls[t] = v;
    __syncthreads();
    for (int off = 1; off < 1024; off <<= 1) {
        unsigned int add = (t >= off) ? ls[t - off] : 0u;
        __syncthreads();
        ls[t] += add;
        __syncthreads();
    }
    if (t < ntiles) tile_off[t] = ls[t] - v; // exclusive
    if (t == 1023) base[n] = ls[1023];       // grand total
}

// in-place safe when base==cnt
__global__ __launch_bounds__(256) void base_write_u32(const unsigned int* __restrict__ cnt,
                                                      const unsigned int* __restrict__ tile_off,
                                                      unsigned int* __restrict__ base, int n) {
    int tid = threadIdx.x;
    int i0 = blockIdx.x * STILE + tid * 4;
    unsigned int c[4];
#pragma unroll
    for (int k = 0; k < 4; ++k) {
        int i = i0 + k;
        c[k] = (i < n) ? cnt[i] : 0u;
    }
    unsigned int s = c[0] + c[1] + c[2] + c[3];
    __shared__ unsigned int ls[256];
    ls[tid] = s;
    __syncthreads();
    for (int off = 1; off < 256; off <<= 1) {
        unsigned int add = (tid >= off) ? ls[tid - off] : 0u;
        __syncthreads();
        ls[tid] += add;
        __syncthreads();
    }
    unsigned int run = (tid > 0 ? ls[tid - 1] : 0u) + tile_off[blockIdx.x];
#pragma unroll
    for (int k = 0; k < 4; ++k) {
        int i = i0 + k;
        if (i < n) base[i] = run;
        run += c[k];
    }
}

// ---------------- pass 2: scatter with LDS ranks (int4 loads) ----------------
// payload = (col, (row&127)<<10 | type)
__global__ __launch_bounds__(512) void scatter4_kernel(
        const int* __restrict__ rows, const int* __restrict__ cols,
        const int* __restrict__ etype, const unsigned* __restrict__ base,
        uint2* __restrict__ payload, int E, int E2, int nrel, int NB, int K) {
    __shared__ unsigned cur[MAXK];
    int tid = threadIdx.x, blk = blockIdx.x;
    for (int i = tid; i < K; i += 512) cur[i] = base[(size_t)i * NB + blk];
    __syncthreads();
    long s = (long)blk * CHUNK4;
    long e = s + CHUNK4; if (e > E2) e = E2;
    long n = e - s;
    if ((n & 3) == 0) {
        const int4* r4 = (const int4*)(rows + s);
        const int4* c4 = (const int4*)(cols + s);
        const int4* t4 = (const int4*)(etype + s);
        int m = (int)(n >> 2);
        for (int i = tid; i < m; i += 512) {
            int4 r = r4[i];
            int4 c = c4[i];
            int4 t = t4[i];
            long e0 = s + ((long)i << 2);
            unsigned pos, ty;
            ty = (unsigned)t.x + ((e0 + 0 < E) ? 0u : (unsigned)nrel);
            pos = atomicAdd(&cur[((unsigned)r.x) >> 7], 1u);
            payload[pos] = make_uint2((unsigned)c.x, (((unsigned)r.x & 127u) << 10) | ty);
            ty = (unsigned)t.y + ((e0 + 1 < E) ? 0u : (unsigned)nrel);
            pos = atomicAdd(&cur[((unsigned)r.y) >> 7], 1u);
            payload[pos] = make_uint2((unsigned)c.y, (((unsigned)r.y & 127u) << 10) | ty);
            ty = (unsigned)t.z + ((e0 + 2 < E) ? 0u : (unsigned)nrel);
            pos = atomicAdd(&cur[((unsigned)r.z) >> 7], 1u);
            payload[pos] = make_uint2((unsigned)c.z, (((unsigned)r.z & 127u) << 10) | ty);
            ty = (unsigned)t.w + ((e0 + 3 < E) ? 0u : (unsigned)nrel);
            pos = atomicAdd(&cur[((unsigned)r.w) >> 7], 1u);
            payload[pos] = make_uint2((unsigned)c.w, (((unsigned)r.w & 127u) << 10) | ty);
        }
    } else {
        for (long i = s + tid; i < e; i += 512) {
            unsigned r = (unsigned)rows[i];
            unsigned c = (unsigned)cols[i];
            unsigned t = (unsigned)etype[i];
            unsigned ty = t + ((i < E) ? 0u : (unsigned)nrel);
            unsigned pos = atomicAdd(&cur[r >> 7], 1u);
            payload[pos] = make_uint2(c, ((r & 127u) << 10) | ty);
        }
    }
}

// ---------------- degrees + per-bucket row offsets; block 0 zeroes BN accumulators ------
__global__ __launch_bounds__(512) void degsort_kernel(
        const unsigned* __restrict__ base, const uint2* __restrict__ payload,
        float* __restrict__ dinvAll, unsigned* __restrict__ rowBase,
        float* __restrict__ bnacc,   // sums|sumsq, 2*D floats
        int nent, int nrel, int NB, int K) {
    __shared__ unsigned h2[RPB * 2];
    __shared__ unsigned sc[RPB];
    int tid = threadIdx.x, b = blockIdx.x;
    if (b == 0 && tid < 2 * D) bnacc[tid] = 0.f;
    if (tid < RPB * 2) h2[tid] = 0;
    __syncthreads();
    size_t NBK = (size_t)NB * K;
    unsigned s = base[(size_t)b * NB];
    unsigned e = (b + 1 < K) ? base[(size_t)(b + 1) * NB] : base[NBK];
    for (unsigned i = s + tid; i < e; i += 512) {
        unsigned y = payload[i].y;
        unsigned lr = (y >> 10) & 127u;
        unsigned fo = ((y & 1023u) >= (unsigned)nrel) ? 1u : 0u;
        atomicAdd(&h2[lr * 2 + fo], 1u);
    }
    __syncthreads();
    unsigned tot = 0;
    if (tid < RPB) { tot = h2[tid * 2] + h2[tid * 2 + 1]; sc[tid] = tot; }
    __syncthreads();
    for (int off = 1; off < RPB; off <<= 1) {
        unsigned v = 0;
        if (tid < RPB && tid >= off) v = sc[tid - off];
        __syncthreads();
        if (tid < RPB) sc[tid] += v;
        __syncthreads();
    }
    if (tid < RPB) {
        rowBase[(size_t)b * RPB + tid] = sc[tid] - tot;   // exclusive prefix
        int row = (b << 7) + tid;
        if (row < nent) {
            unsigned a = h2[tid * 2], o = h2[tid * 2 + 1];
            dinvAll[row]        = a ? rsqrtf((float)a) : 0.f;
            dinvAll[nent + row] = o ? rsqrtf((float)o) : 0.f;
        }
    }
}

// ---------------- per-bucket reorder + register accumulate (R14/R16 form) ----------
__global__ __launch_bounds__(512) void accum4_kernel(
        const unsigned* __restrict__ base, const uint2* __restrict__ payload,
        const unsigned short* __restrict__ T_bf, const float* __restrict__ dinvAll,
        const unsigned* __restrict__ rowBase,
        float* __restrict__ out, unsigned short* __restrict__ h_bf, int use_bf,
        float* __restrict__ sums, float* __restrict__ sumsq,
        int nent, int nrel, int NB, int K) {
    __shared__ uint2 sp[CAP];              // 20 KB
    __shared__ unsigned hstart[RPB];
    __shared__ unsigned hcur[RPB];
    __shared__ float ls[D], lq[D];
    int tid = threadIdx.x;
    int b = blockIdx.x;
    size_t NBK = (size_t)NB * K;
    unsigned start = base[(size_t)b * NB];
    unsigned end   = (b + 1 < K) ? base[(size_t)(b + 1) * NB] : base[NBK];
    int n = (int)(end - start);
    int nin = n < CAP ? n : CAP;

    if (tid < RPB) { ls[tid] = 0.f; lq[tid] = 0.f; }

    if (n <= CAP) {
        if (tid < RPB) {
            unsigned v = rowBase[(size_t)b * RPB + tid];
            hstart[tid] = v;
            hcur[tid] = v;
        }
        __syncthreads();
        for (int i = tid; i < nin; i += 512) {
            uint2 p = payload[start + i];
            unsigned pos = atomicAdd(&hcur[(p.y >> 10) & 127u], 1u);
            sp[pos] = p;
        }
        __syncthreads();
    } else {
        if (tid < RPB) hstart[tid] = 0;
        __syncthreads();
        for (int i = tid; i < nin; i += 512)
            atomicAdd(&hstart[(payload[start + i].y >> 10) & 127u], 1u);
        __syncthreads();
        for (int off = 1; off < RPB; off <<= 1) {
            unsigned v = 0;
            if (tid < RPB && tid >= off) v = hstart[tid - off];
            __syncthreads();
            if (tid < RPB) hstart[tid] += v;
            __syncthreads();
        }
        unsigned ex = 0;
        if (tid < RPB) ex = tid ? hstart[tid - 1] : 0u;
        __syncthreads();
        if (tid < RPB) { hstart[tid] = ex; hcur[tid] = ex; }
        __syncthreads();
        for (int i = tid; i < nin; i += 512) {
            uint2 p = payload[start + i];
            unsigned pos = atomicAdd(&hcur[(p.y >> 10) & 127u], 1u);
            sp[pos] = p;
        }
        __syncthreads();
    }

    const uint2* T2 = (const uint2*)T_bf;   // one row = 128 bf16 = 32 uint2
    float4* out4 = (float4*)out;
    uint2* hb2 = (uint2*)h_bf;
    int hw = tid >> 5, l32 = tid & 31;
    int row0 = b << 7;
    unsigned unrel = (unsigned)nrel;
    float4 s4 = make_float4(0.f, 0.f, 0.f, 0.f);
    float4 q4 = make_float4(0.f, 0.f, 0.f, 0.f);
    for (int rr = 0; rr < 8; ++rr) {
        int r = (hw << 3) + rr;
        int row = row0 + r;
        float da_in = 0.f, da_out = 0.f;
        if (row < nent) { da_in = dinvAll[row]; da_out = dinvAll[nent + row]; }
        unsigned s0 = hstart[r];
        unsigned s1 = (r < RPB - 1) ? hstart[r + 1] : (unsigned)nin;
        float4 a = make_float4(0.f, 0.f, 0.f, 0.f);
        unsigned i = s0;
        for (; i + 4 <= s1; i += 4) {      // 4-deep independent chains
            uint2 p0 = sp[i], p1 = sp[i + 1], p2 = sp[i + 2], p3 = sp[i + 3];
            unsigned ty0 = p0.y & 1023u, ty1 = p1.y & 1023u;
            unsigned ty2 = p2.y & 1023u, ty3 = p3.y & 1023u;
            bool f0 = ty0 < unrel, f1 = ty1 < unrel, f2 = ty2 < unrel, f3 = ty3 < unrel;
            float dc0 = dinvAll[(f0 ? 0 : nent) + p0.x];
            float dc1 = dinvAll[(f1 ? 0 : nent) + p1.x];
            float dc2 = dinvAll[(f2 ? 0 : nent) + p2.x];
            float dc3 = dinvAll[(f3 ? 0 : nent) + p3.x];
            uint2 t0 = T2[(size_t)ty0 * 32 + l32];
            uint2 t1 = T2[(size_t)ty1 * 32 + l32];
            uint2 t2 = T2[(size_t)ty2 * 32 + l32];
            uint2 t3 = T2[(size_t)ty3 * 32 + l32];
            float c0 = 0.5f * (f0 ? da_in : da_out) * dc0;
            float c1 = 0.5f * (f1 ? da_in : da_out) * dc1;
            float c2 = 0.5f * (f2 ? da_in : da_out) * dc2;
            float c3 = 0.5f * (f3 ? da_in : da_out) * dc3;
            FMA4(a, c0, t0) FMA4(a, c1, t1) FMA4(a, c2, t2) FMA4(a, c3, t3)
        }
        for (; i < s1; ++i) {
            uint2 p = sp[i];
            unsigned ty = p.y & 1023u;
            bool f = ty < unrel;
            float c = 0.5f * (f ? da_in : da_out) * dinvAll[(f ? 0 : nent) + p.x];
            uint2 t = T2[(size_t)ty * 32 + l32];
            FMA4(a, c, t)
        }
        // overflow tail (n > CAP): correctness fallback
        for (unsigned j = start + (unsigned)nin; j < end; ++j) {
            uint2 p = payload[j];
            if (((p.y >> 10) & 127u) == (unsigned)r) {
                unsigned ty = p.y & 1023u;
                bool f = ty < unrel;
                float c = 0.5f * (f ? da_in : da_out) * dinvAll[(f ? 0 : nent) + p.x];
                uint2 t = T2[(size_t)ty * 32 + l32];
                FMA4(a, c, t)
            }
        }
        if (row < nent) {
            if (use_bf) {
                hb2[(size_t)row * 32 + l32] = make_uint2(
                    f2bf_rne(a.x) | (f2bf_rne(a.y) << 16),
                    f2bf_rne(a.z) | (f2bf_rne(a.w) << 16));
            } else {
                out4[(size_t)row * 32 + l32] = a;
            }
            s4.x += a.x; s4.y += a.y; s4.z += a.z; s4.w += a.w;
            q4.x += a.x * a.x; q4.y += a.y * a.y; q4.z += a.z * a.z; q4.w += a.w * a.w;
        }
    }
    atomicAdd(&ls[4 * l32 + 0], s4.x); atomicAdd(&ls[4 * l32 + 1], s4.y);
    atomicAdd(&ls[4 * l32 + 2], s4.z); atomicAdd(&ls[4 * l32 + 3], s4.w);
    atomicAdd(&lq[4 * l32 + 0], q4.x); atomicAdd(&lq[4 * l32 + 1], q4.y);
    atomicAdd(&lq[4 * l32 + 2], q4.z); atomicAdd(&lq[4 * l32 + 3], q4.w);
    __syncthreads();
    if (tid < D) {
        atomicAdd(&sums[tid], ls[tid]);
        atomicAdd(&sumsq[tid], lq[tid]);
    }
}

// ---------------- BN apply with fused coefficient computation ----------------
// bf16-h variant: read bf16 h, write f32 out; fused rel_embed passthrough
__global__ __launch_bounds__(256) void bn_apply2_bf_kernel(
        const unsigned short* __restrict__ h_bf, float* __restrict__ out,
        const float* __restrict__ sums, const float* __restrict__ sumsq,
        const float* __restrict__ gamma, const float* __restrict__ beta,
        const float* __restrict__ rel_embed, float* __restrict__ pass, int nent, int npass4) {
    __shared__ float s_sc[D], s_sh[D];
    if (threadIdx.x < D) {
        int c = threadIdx.x;
        float inv_n = 1.0f / (float)nent;
        float mean = sums[c] * inv_n;
        float var = sumsq[c] * inv_n - mean * mean;
        float istd = rsqrtf(var + 1e-5f);
        float sc = istd * gamma[c];
        s_sc[c] = sc;
        s_sh[c] = beta[c] - mean * sc;
    }
    __syncthreads();
    long total = (long)nent * 32;   // uint2 units (4 elems each)
    long stride = (long)gridDim.x * blockDim.x;
    long idx0 = (long)blockIdx.x * blockDim.x + threadIdx.x;
    const uint2* hb2 = (const uint2*)h_bf;
    float4* out4 = (float4*)out;
    for (long i = idx0; i < total; i += stride) {
        int c0 = (int)((i & 31) << 2);
        uint2 v = hb2[i];
        float4 o;
        o.x = tanhf(__uint_as_float(v.x << 16)         * s_sc[c0 + 0] + s_sh[c0 + 0]);
        o.y = tanhf(__uint_as_float(v.x & 0xffff0000u) * s_sc[c0 + 1] + s_sh[c0 + 1]);
        o.z = tanhf(__uint_as_float(v.y << 16)         * s_sc[c0 + 2] + s_sh[c0 + 2]);
        o.w = tanhf(__uint_as_float(v.y & 0xffff0000u) * s_sc[c0 + 3] + s_sh[c0 + 3]);
        out4[i] = o;
    }
    const float4* re4 = (const float4*)rel_embed;
    float4* p4 = (float4*)pass;
    for (long i = idx0; i < npass4; i += stride) p4[i] = re4[i];
}

// f32 variant (when ws can't hold h_bf)
__global__ __launch_bounds__(256) void bn_apply2_kernel(
        float* __restrict__ h,
        const float* __restrict__ sums, const float* __restrict__ sumsq,
        const float* __restrict__ gamma, const float* __restrict__ beta,
        const float* __restrict__ rel_embed, float* __restrict__ pass, int nent, int npass4) {
    __shared__ float s_sc[D], s_sh[D];
    if (threadIdx.x < D) {
        int c = threadIdx.x;
        float inv_n = 1.0f / (float)nent;
        float mean = sums[c] * inv_n;
        float var = sumsq[c] * inv_n - mean * mean;
        float istd = rsqrtf(var + 1e-5f);
        float sc = istd * gamma[c];
        s_sc[c] = sc;
        s_sh[c] = beta[c] - mean * sc;
    }
    __syncthreads();
    long total = (long)nent * (D / 4);
    long stride = (long)gridDim.x * blockDim.x;
    long idx0 = (long)blockIdx.x * blockDim.x + threadIdx.x;
    float4* h4 = (float4*)h;
    for (long i = idx0; i < total; i += stride) {
        int c0 = (int)((i & 31) << 2);
        float4 v = h4[i];
        v.x = tanhf(v.x * s_sc[c0 + 0] + s_sh[c0 + 0]);
        v.y = tanhf(v.y * s_sc[c0 + 1] + s_sh[c0 + 1]);
        v.z = tanhf(v.z * s_sc[c0 + 2] + s_sh[c0 + 2]);
        v.w = tanhf(v.w * s_sc[c0 + 3] + s_sh[c0 + 3]);
        h4[i] = v;
    }
    const float4* re4 = (const float4*)rel_embed;
    float4* p4 = (float4*)pass;
    for (long i = idx0; i < npass4; i += stride) p4[i] = re4[i];
}

// ---------------- fallback (atomic) path kernels ----------------
__global__ __launch_bounds__(256) void degree_kernel(const int* __restrict__ rows, int E,
                                                     float* __restrict__ deg_in,
                                                     float* __restrict__ deg_out) {
    int total = 2 * E;
    int tid = blockIdx.x * blockDim.x + threadIdx.x;
    int nth = gridDim.x * blockDim.x;
    for (long b = (long)tid * BUNROLL; b < total; b += (long)nth * BUNROLL) {
        for (int k = 0; k < BUNROLL && b + k < total; ++k) {
            int r = rows[b + k];
            float* deg = (b + k < E) ? deg_in : deg_out;
            atomicAdd(&deg[r], 1.0f);
        }
    }
}

__global__ void scatter_kernel(const int* __restrict__ rows, const int* __restrict__ cols,
                               const int* __restrict__ etype,
                               const float* __restrict__ deg_in, const float* __restrict__ deg_out,
                               const float* __restrict__ T_in, const float* __restrict__ T_out,
                               float* __restrict__ out, int E) {
    int wave = (blockIdx.x * blockDim.x + threadIdx.x) >> 6;
    int lane = threadIdx.x & 63;
    int nwaves = (gridDim.x * blockDim.x) >> 6;
    int total = 2 * E;
    for (int e = wave; e < total; e += nwaves) {
        bool first = (e < E);
        int row = rows[e];
        int col = cols[e];
        int t = etype[e];
        const float* deg = first ? deg_in : deg_out;
        const float* T = first ? T_in : T_out;
        float dr = deg[row];
        float dc = deg[col];
        float norm = (dr > 0.f ? rsqrtf(dr) : 0.f) * (dc > 0.f ? rsqrtf(dc) : 0.f);
        float c = 0.5f * norm;
        if (c != 0.f) {
            float v0 = c * T[t * D + lane];
            float v1 = c * T[t * D + 64 + lane];
            long b = (long)row * D;
            atomicAdd(&out[b + lane], v0);
            atomicAdd(&out[b + 64 + lane], v1);
        }
    }
}

__global__ void bn_stats_kernel(const float* __restrict__ h, int nent,
                                float* __restrict__ sums, float* __restrict__ sumsq) {
    int col = threadIdx.x;
    float s = 0.f, s2 = 0.f;
    for (int r = blockIdx.x; r < nent; r += gridDim.x) {
        float v = h[(long)r * D + col];
        s += v;
        s2 += v * v;
    }
    atomicAdd(&sums[col], s);
    atomicAdd(&sumsq[col], s2);
}

__global__ void bn_apply_kernel(float* __restrict__ h,
                                const float* __restrict__ sums, const float* __restrict__ sumsq,
                                const float* __restrict__ gamma, const float* __restrict__ beta,
                                int nent) {
    long total = ((long)nent * D) / 4;
    long stride = (long)gridDim.x * blockDim.x;
    float inv_n = 1.0f / (float)nent;
    float4* h4 = (float4*)h;
    for (long i = (long)blockIdx.x * blockDim.x + threadIdx.x; i < total; i += stride) {
        int c0 = (int)((i * 4) & (D - 1));
        float4 v = h4[i];
        float r[4] = {v.x, v.y, v.z, v.w};
#pragma unroll
        for (int j = 0; j < 4; ++j) {
            int col = c0 + j;
            float mean = sums[col] * inv_n;
            float var = sumsq[col] * inv_n - mean * mean;
            float istd = rsqrtf(var + 1e-5f);
            r[j] = tanhf((r[j] - mean) * istd * gamma[col] + beta[col]);
        }
        h4[i] = make_float4(r[0], r[1], r[2], r[3]);
    }
}

extern "C" void kernel_launch(void* const* d_in, const int* in_sizes, int n_in,
                              void* d_out, int out_size, void* d_ws, size_t ws_size,
                              hipStream_t stream) {
    const float* rel_embed     = (const float*)d_in[0];
    const float* rel_embed_in  = (const float*)d_in[1];
    const float* rel_embed_out = (const float*)d_in[2];
    const float* w_in          = (const float*)d_in[3];
    const float* w_out         = (const float*)d_in[4];
    const float* bn_gamma      = (const float*)d_in[5];
    const float* bn_beta       = (const float*)d_in[6];
    const int*   edge_index    = (const int*)d_in[7];
    const int*   edge_type     = (const int*)d_in[8];

    const int nrel = in_sizes[0] / D;               // 500
    const int E2   = in_sizes[8];                   // 3,000,000
    const int E    = E2 / 2;                        // 1,500,000
    const int nent = (out_size - in_sizes[0]) / D;  // 200,000
    const int K    = (nent + RPB - 1) / RPB;        // 1563 buckets
    const int NB   = (E2 + CHUNK4 - 1) / CHUNK4;    // 184 blocks
    const long NBK = (long)NB * K;                  // ~288K counters
    const int ntiles = (int)((NBK + STILE - 1) / STILE);  // ~281

    float* out = (float*)d_out;
    const int* rows = edge_index;
    const int* cols = edge_index + E2;

    // ---- workspace layout (fast path) ----
    float*          ws       = (float*)d_ws;
    float*          dinvAll  = ws;                                   // 2*nent
    float*          sums     = dinvAll + (size_t)2 * nent;           // D
    float*          sumsq    = sums + D;                             // D
    unsigned*       rowBase  = (unsigned*)(sumsq + D);               // K*RPB
    unsigned*       cnt      = rowBase + (size_t)K * RPB;            // NBK+1 (scan in place)
    unsigned*       tsum     = cnt + NBK + 1;                        // ntiles
    unsigned*       toff     = tsum + ntiles;                        // ntiles
    unsigned short* T_bf     = (unsigned short*)(toff + ntiles);     // 2*nrel*D bf16
    uintptr_t pal = ((uintptr_t)(T_bf + (size_t)2 * nrel * D) + 15) & ~(uintptr_t)15;
    uint2*          payload  = (uint2*)pal;                          // E2
    uintptr_t pal2 = ((uintptr_t)(payload + E2) + 15) & ~(uintptr_t)15;
    unsigned short* h_bf     = (unsigned short*)pal2;                // nent*D bf16 (optional)
    size_t needed    = pal2 - (uintptr_t)d_ws;
    size_t needed_bf = needed + (size_t)nent * D * sizeof(unsigned short);

    bool fast   = (needed <= ws_size) && (K <= MAXK) && (2 * nrel <= 1024) &&
                  (ntiles <= 1024);
    int  use_bf = fast && (needed_bf <= ws_size);

    if (fast) {
        transform2_bf_kernel<<<2 * nrel, D, 0, stream>>>(rel_embed_in, w_in,
                                                         rel_embed_out, w_out, T_bf, nrel);
        hist4_kernel<<<NB, 512, 0, stream>>>(rows, E2, cnt, NB, K);
        tile_sum_u32<<<ntiles, 256, 0, stream>>>(cnt, tsum, (int)NBK);
        scan_tiles_kernel<<<1, 1024, 0, stream>>>(tsum, toff, cnt, ntiles, (int)NBK);
        base_write_u32<<<ntiles, 256, 0, stream>>>(cnt, toff, cnt, (int)NBK);
        scatter4_kernel<<<NB, 512, 0, stream>>>(rows, cols, edge_type, cnt,
                                                payload, E, E2, nrel, NB, K);
        degsort_kernel<<<K, 512, 0, stream>>>(cnt, payload, dinvAll, rowBase, sums,
                                              nent, nrel, NB, K);
        accum4_kernel<<<K, 512, 0, stream>>>(cnt, payload, T_bf, dinvAll, rowBase,
                                             out, h_bf, use_bf, sums, sumsq,
                                             nent, nrel, NB, K);
        if (use_bf) {
            bn_apply2_bf_kernel<<<2048, 256, 0, stream>>>(h_bf, out, sums, sumsq,
                                                          bn_gamma, bn_beta, rel_embed,
                                                          out + (size_t)nent * D, nent,
                                                          (nrel * D) / 4);
        } else {
            bn_apply2_kernel<<<2048, 256, 0, stream>>>(out, sums, sumsq,
                                                       bn_gamma, bn_beta, rel_embed,
                                                       out + (size_t)nent * D, nent,
                                                       (nrel * D) / 4);
        }
    } else {
        // ---------- fallback atomic path (f32 everywhere) ----------
        float* f_deg_in  = ws;
        float* f_deg_out = f_deg_in + nent;
        float* f_T_in    = f_deg_out + nent;
        float* f_T_out   = f_T_in + (size_t)nrel * D;
        float* f_sums    = f_T_out + (size_t)nrel * D;
        float* f_sumsq   = f_sums + D;

        hipMemsetAsync(out, 0, (size_t)nent * D * sizeof(float), stream);
        hipMemsetAsync(f_deg_in, 0, (size_t)2 * nent * sizeof(float), stream);
        hipMemsetAsync(f_sums, 0, (size_t)2 * D * sizeof(float), stream);

        transform2_kernel<<<2 * nrel, D, 0, stream>>>(rel_embed_in, w_in, rel_embed_out, w_out,
                                                      f_T_in, nrel);
        degree_kernel<<<1466, 256, 0, stream>>>(edge_index, E, f_deg_in, f_deg_out);
        scatter_kernel<<<2048, 256, 0, stream>>>(rows, cols, edge_type, f_deg_in, f_deg_out,
                                                 f_T_in, f_T_out, out, E);
        bn_stats_kernel<<<1024, D, 0, stream>>>(out, nent, f_sums, f_sumsq);
        bn_apply_kernel<<<4096, 256, 0, stream>>>(out, f_sums, f_sumsq, bn_gamma, bn_beta, nent);
        hipMemcpyAsync(out + (size_t)nent * D, rel_embed,
                       (size_t)nrel * D * sizeof(float), hipMemcpyDeviceToDevice, stream);
    }
}

// Round 18
// 205.283 us; speedup vs baseline: 1.5730x; 1.0000x over previous
//
#include <hip/hip_runtime.h>

#define D 128
#define BUNROLL 8
#define RPB 128                 // rows per bucket
#define CAP 2560                // max edges sorted in LDS per bucket (avg ~1920)
#define MAXK 2048               // max buckets (LDS histogram size)
#define CHUNK4 16384            // edges per block in hist/scatter (identical mapping!)
#define STILE 1024              // scan tile

__device__ __forceinline__ unsigned f2bf_rne(float x) {
    unsigned u = __float_as_uint(x);
    return (u + 0x7fffu + ((u >> 16) & 1u)) >> 16;
}

#define FMA4(a, c, t)                                        \
    (a).x += (c) * __uint_as_float((t).x << 16);             \
    (a).y += (c) * __uint_as_float((t).x & 0xffff0000u);     \
    (a).z += (c) * __uint_as_float((t).y << 16);             \
    (a).w += (c) * __uint_as_float((t).y & 0xffff0000u);

// f32 transform (fallback path)
__global__ void transform2_kernel(const float* __restrict__ Rin, const float* __restrict__ Win,
                                  const float* __restrict__ Rout, const float* __restrict__ Wout,
                                  float* __restrict__ T_all, int nrel) {
    __shared__ float row[D];
    int b = blockIdx.x;
    bool second = (b >= nrel);
    const float* R = second ? Rout : Rin;
    const float* W = second ? Wout : Win;
    int r = second ? b - nrel : b;
    int t = threadIdx.x;
    row[t] = R[r * D + t];
    __syncthreads();
    float acc = 0.f;
#pragma unroll 8
    for (int k = 0; k < D; ++k) acc += row[k] * W[k * D + t];
    T_all[(size_t)b * D + t] = acc;
}

// ---------------- fused: relation transform (blocks 0..NT4-1) + bucket histogram ----------
// transform blocks: 4 table-rows each (512 threads = 4 x 128)
// hist blocks: per-block LDS histogram over CHUNK4 edges, 8-wide int4 loads
__global__ __launch_bounds__(512) void fused_th_kernel(
        const float* __restrict__ Rin, const float* __restrict__ Win,
        const float* __restrict__ Rout, const float* __restrict__ Wout,
        unsigned short* __restrict__ T_bf, int nrel, int NT4,
        const int* __restrict__ rows, int E2,
        unsigned* __restrict__ cnt, int NB, int K) {
    __shared__ unsigned shmem[MAXK];   // hist: counters; transform: aliased row buffer
    int tid = threadIdx.x;
    if (blockIdx.x < NT4) {
        // ---- transform role ----
        float* rowbuf = (float*)shmem;           // 4 x 128 floats
        int sub = tid >> 7;                      // 0..3
        int t = tid & 127;
        int b = blockIdx.x * 4 + sub;            // table row
        bool valid = (b < 2 * nrel);
        bool second = valid && (b >= nrel);
        const float* R = second ? Rout : Rin;
        const float* W = second ? Wout : Win;
        int r = second ? b - nrel : b;
        if (valid) rowbuf[sub * D + t] = R[(size_t)r * D + t];
        __syncthreads();
        if (valid) {
            float acc = 0.f;
#pragma unroll 8
            for (int k = 0; k < D; ++k) acc += rowbuf[sub * D + k] * W[k * D + t];
            T_bf[(size_t)b * D + t] = (unsigned short)f2bf_rne(acc);
        }
        return;
    }
    // ---- histogram role ----
    int blk = blockIdx.x - NT4;
    for (int i = tid; i < K; i += 512) shmem[i] = 0;
    __syncthreads();
    long s = (long)blk * CHUNK4;
    long e = s + CHUNK4; if (e > E2) e = E2;
    long n = e - s;
    if ((n & 7) == 0) {
        const int4* r4 = (const int4*)(rows + s);
        int m2 = (int)(n >> 3);
        for (int i = tid; i < m2; i += 512) {
            int4 ra = r4[2 * i];
            int4 rb = r4[2 * i + 1];
            atomicAdd(&shmem[((unsigned)ra.x) >> 7], 1u);
            atomicAdd(&shmem[((unsigned)ra.y) >> 7], 1u);
            atomicAdd(&shmem[((unsigned)ra.z) >> 7], 1u);
            atomicAdd(&shmem[((unsigned)ra.w) >> 7], 1u);
            atomicAdd(&shmem[((unsigned)rb.x) >> 7], 1u);
            atomicAdd(&shmem[((unsigned)rb.y) >> 7], 1u);
            atomicAdd(&shmem[((unsigned)rb.z) >> 7], 1u);
            atomicAdd(&shmem[((unsigned)rb.w) >> 7], 1u);
        }
    } else {
        for (long i = s + tid; i < e; i += 512)
            atomicAdd(&shmem[((unsigned)rows[i]) >> 7], 1u);
    }
    __syncthreads();
    for (int i = tid; i < K; i += 512)
        cnt[(size_t)i * NB + blk] = shmem[i];
}

// ---------------- device-wide scan over n=NB*K counters ----------------
__global__ __launch_bounds__(256) void tile_sum_u32(const unsigned int* __restrict__ cnt,
                                                    unsigned int* __restrict__ tsum, int n) {
    int tid = threadIdx.x;
    int i0 = blockIdx.x * STILE + tid * 4;
    unsigned int s = 0;
#pragma unroll
    for (int k = 0; k < 4; ++k) {
        int i = i0 + k;
        if (i < n) s += cnt[i];
    }
    __shared__ unsigned int ls[256];
    ls[tid] = s;
    __syncthreads();
    for (int off = 128; off >= 1; off >>= 1) {
        if (tid < off) ls[tid] += ls[tid + off];
        __syncthreads();
    }
    if (tid == 0) tsum[blockIdx.x] = ls[0];
}

__global__ void scan_tiles_kernel(const unsigned int* __restrict__ tile_sums,
                                  unsigned int* __restrict__ tile_off,
                                  unsigned int* __restrict__ base, int ntiles, int n) {
    int t = threadIdx.x; // blockDim = 1024
    __shared__ unsigned int ls[1024];
    unsigned int v = (t < ntiles) ? tile_sums[t] : 0u;
    ls[t] = v;
    __syncthreads();
    for (int off = 1; off < 1024; off <<= 1) {
        unsigned int add = (t >= off) ? ls[t - off] : 0u;
        __syncthreads();
        ls[t] += add;
        __syncthreads();
    }
    if (t < ntiles) tile_off[t] = ls[t] - v; // exclusive
    if (t == 1023) base[n] = ls[1023];       // grand total
}

// in-place safe when base==cnt
__global__ __launch_bounds__(256) void base_write_u32(const unsigned int* __restrict__ cnt,
                                                      const unsigned int* __restrict__ tile_off,
                                                      unsigned int* __restrict__ base, int n) {
    int tid = threadIdx.x;
    int i0 = blockIdx.x * STILE + tid * 4;
    unsigned int c[4];
#pragma unroll
    for (int k = 0; k < 4; ++k) {
        int i = i0 + k;
        c[k] = (i < n) ? cnt[i] : 0u;
    }
    unsigned int s = c[0] + c[1] + c[2] + c[3];
    __shared__ unsigned int ls[256];
    ls[tid] = s;
    __syncthreads();
    for (int off = 1; off < 256; off <<= 1) {
        unsigned int add = (tid >= off) ? ls[tid - off] : 0u;
        __syncthreads();
        ls[tid] += add;
        __syncthreads();
    }
    unsigned int run = (tid > 0 ? ls[tid - 1] : 0u) + tile_off[blockIdx.x];
#pragma unroll
    for (int k = 0; k < 4; ++k) {
        int i = i0 + k;
        if (i < n) base[i] = run;
        run += c[k];
    }
}

#define SCAT1(rr, cc, tt, off)                                                     \
    {                                                                              \
        unsigned ty = (unsigned)(tt) + ((e0 + (off) < E) ? 0u : (unsigned)nrel);   \
        unsigned pos = atomicAdd(&cur[((unsigned)(rr)) >> 7], 1u);                 \
        payload[pos] = make_uint2((unsigned)(cc), (((unsigned)(rr) & 127u) << 10) | ty); \
    }

// ---------------- pass 2: scatter with LDS ranks (8-wide int4 loads) ----------------
// payload = (col, (row&127)<<10 | type)
__global__ __launch_bounds__(512) void scatter4_kernel(
        const int* __restrict__ rows, const int* __restrict__ cols,
        const int* __restrict__ etype, const unsigned* __restrict__ base,
        uint2* __restrict__ payload, int E, int E2, int nrel, int NB, int K) {
    __shared__ unsigned cur[MAXK];
    int tid = threadIdx.x, blk = blockIdx.x;
    for (int i = tid; i < K; i += 512) cur[i] = base[(size_t)i * NB + blk];
    __syncthreads();
    long s = (long)blk * CHUNK4;
    long e = s + CHUNK4; if (e > E2) e = E2;
    long n = e - s;
    if ((n & 7) == 0) {
        const int4* r4 = (const int4*)(rows + s);
        const int4* c4 = (const int4*)(cols + s);
        const int4* t4 = (const int4*)(etype + s);
        int m2 = (int)(n >> 3);
        for (int i = tid; i < m2; i += 512) {
            int4 ra = r4[2 * i], rb = r4[2 * i + 1];
            int4 ca = c4[2 * i], cb = c4[2 * i + 1];
            int4 ta = t4[2 * i], tb = t4[2 * i + 1];
            long e0 = s + ((long)i << 3);
            SCAT1(ra.x, ca.x, ta.x, 0) SCAT1(ra.y, ca.y, ta.y, 1)
            SCAT1(ra.z, ca.z, ta.z, 2) SCAT1(ra.w, ca.w, ta.w, 3)
            SCAT1(rb.x, cb.x, tb.x, 4) SCAT1(rb.y, cb.y, tb.y, 5)
            SCAT1(rb.z, cb.z, tb.z, 6) SCAT1(rb.w, cb.w, tb.w, 7)
        }
    } else {
        for (long i = s + tid; i < e; i += 512) {
            unsigned r = (unsigned)rows[i];
            unsigned c = (unsigned)cols[i];
            unsigned t = (unsigned)etype[i];
            unsigned ty = t + ((i < E) ? 0u : (unsigned)nrel);
            unsigned pos = atomicAdd(&cur[r >> 7], 1u);
            payload[pos] = make_uint2(c, ((r & 127u) << 10) | ty);
        }
    }
}

// ---------------- degrees + per-bucket row offsets (4-wide); blk 0 zeroes BN acc --------
__global__ __launch_bounds__(512) void degsort_kernel(
        const unsigned* __restrict__ base, const uint2* __restrict__ payload,
        float* __restrict__ dinvAll, unsigned* __restrict__ rowBase,
        float* __restrict__ bnacc,   // sums|sumsq, 2*D floats
        int nent, int nrel, int NB, int K) {
    __shared__ unsigned h2[RPB * 2];
    __shared__ unsigned sc[RPB];
    int tid = threadIdx.x, b = blockIdx.x;
    if (b == 0 && tid < 2 * D) bnacc[tid] = 0.f;
    if (tid < RPB * 2) h2[tid] = 0;
    __syncthreads();
    size_t NBK = (size_t)NB * K;
    unsigned s = base[(size_t)b * NB];
    unsigned e = (b + 1 < K) ? base[(size_t)(b + 1) * NB] : base[NBK];
    unsigned un = (unsigned)nrel;
    for (unsigned i0 = s + tid * 4; i0 < e; i0 += 512u * 4u) {
        if (i0 + 3 < e) {
            unsigned y0 = payload[i0].y;
            unsigned y1 = payload[i0 + 1].y;
            unsigned y2 = payload[i0 + 2].y;
            unsigned y3 = payload[i0 + 3].y;
            atomicAdd(&h2[((y0 >> 10) & 127u) * 2 + (((y0 & 1023u) >= un) ? 1u : 0u)], 1u);
            atomicAdd(&h2[((y1 >> 10) & 127u) * 2 + (((y1 & 1023u) >= un) ? 1u : 0u)], 1u);
            atomicAdd(&h2[((y2 >> 10) & 127u) * 2 + (((y2 & 1023u) >= un) ? 1u : 0u)], 1u);
            atomicAdd(&h2[((y3 >> 10) & 127u) * 2 + (((y3 & 1023u) >= un) ? 1u : 0u)], 1u);
        } else {
            for (unsigned j = i0; j < e; ++j) {
                unsigned y = payload[j].y;
                atomicAdd(&h2[((y >> 10) & 127u) * 2 + (((y & 1023u) >= un) ? 1u : 0u)], 1u);
            }
        }
    }
    __syncthreads();
    unsigned tot = 0;
    if (tid < RPB) { tot = h2[tid * 2] + h2[tid * 2 + 1]; sc[tid] = tot; }
    __syncthreads();
    for (int off = 1; off < RPB; off <<= 1) {
        unsigned v = 0;
        if (tid < RPB && tid >= off) v = sc[tid - off];
        __syncthreads();
        if (tid < RPB) sc[tid] += v;
        __syncthreads();
    }
    if (tid < RPB) {
        rowBase[(size_t)b * RPB + tid] = sc[tid] - tot;   // exclusive prefix
        int row = (b << 7) + tid;
        if (row < nent) {
            unsigned a = h2[tid * 2], o = h2[tid * 2 + 1];
            dinvAll[row]        = a ? rsqrtf((float)a) : 0.f;
            dinvAll[nent + row] = o ? rsqrtf((float)o) : 0.f;
        }
    }
}

// ---------------- per-bucket reorder + register accumulate (R14/R16 form, FROZEN) --------
__global__ __launch_bounds__(512) void accum4_kernel(
        const unsigned* __restrict__ base, const uint2* __restrict__ payload,
        const unsigned short* __restrict__ T_bf, const float* __restrict__ dinvAll,
        const unsigned* __restrict__ rowBase,
        float* __restrict__ out, unsigned short* __restrict__ h_bf, int use_bf,
        float* __restrict__ sums, float* __restrict__ sumsq,
        int nent, int nrel, int NB, int K) {
    __shared__ uint2 sp[CAP];              // 20 KB
    __shared__ unsigned hstart[RPB];
    __shared__ unsigned hcur[RPB];
    __shared__ float ls[D], lq[D];
    int tid = threadIdx.x;
    int b = blockIdx.x;
    size_t NBK = (size_t)NB * K;
    unsigned start = base[(size_t)b * NB];
    unsigned end   = (b + 1 < K) ? base[(size_t)(b + 1) * NB] : base[NBK];
    int n = (int)(end - start);
    int nin = n < CAP ? n : CAP;

    if (tid < RPB) { ls[tid] = 0.f; lq[tid] = 0.f; }

    if (n <= CAP) {
        if (tid < RPB) {
            unsigned v = rowBase[(size_t)b * RPB + tid];
            hstart[tid] = v;
            hcur[tid] = v;
        }
        __syncthreads();
        for (int i = tid; i < nin; i += 512) {
            uint2 p = payload[start + i];
            unsigned pos = atomicAdd(&hcur[(p.y >> 10) & 127u], 1u);
            sp[pos] = p;
        }
        __syncthreads();
    } else {
        if (tid < RPB) hstart[tid] = 0;
        __syncthreads();
        for (int i = tid; i < nin; i += 512)
            atomicAdd(&hstart[(payload[start + i].y >> 10) & 127u], 1u);
        __syncthreads();
        for (int off = 1; off < RPB; off <<= 1) {
            unsigned v = 0;
            if (tid < RPB && tid >= off) v = hstart[tid - off];
            __syncthreads();
            if (tid < RPB) hstart[tid] += v;
            __syncthreads();
        }
        unsigned ex = 0;
        if (tid < RPB) ex = tid ? hstart[tid - 1] : 0u;
        __syncthreads();
        if (tid < RPB) { hstart[tid] = ex; hcur[tid] = ex; }
        __syncthreads();
        for (int i = tid; i < nin; i += 512) {
            uint2 p = payload[start + i];
            unsigned pos = atomicAdd(&hcur[(p.y >> 10) & 127u], 1u);
            sp[pos] = p;
        }
        __syncthreads();
    }

    const uint2* T2 = (const uint2*)T_bf;   // one row = 128 bf16 = 32 uint2
    float4* out4 = (float4*)out;
    uint2* hb2 = (uint2*)h_bf;
    int hw = tid >> 5, l32 = tid & 31;
    int row0 = b << 7;
    unsigned unrel = (unsigned)nrel;
    float4 s4 = make_float4(0.f, 0.f, 0.f, 0.f);
    float4 q4 = make_float4(0.f, 0.f, 0.f, 0.f);
    for (int rr = 0; rr < 8; ++rr) {
        int r = (hw << 3) + rr;
        int row = row0 + r;
        float da_in = 0.f, da_out = 0.f;
        if (row < nent) { da_in = dinvAll[row]; da_out = dinvAll[nent + row]; }
        unsigned s0 = hstart[r];
        unsigned s1 = (r < RPB - 1) ? hstart[r + 1] : (unsigned)nin;
        float4 a = make_float4(0.f, 0.f, 0.f, 0.f);
        unsigned i = s0;
        for (; i + 4 <= s1; i += 4) {      // 4-deep independent chains
            uint2 p0 = sp[i], p1 = sp[i + 1], p2 = sp[i + 2], p3 = sp[i + 3];
            unsigned ty0 = p0.y & 1023u, ty1 = p1.y & 1023u;
            unsigned ty2 = p2.y & 1023u, ty3 = p3.y & 1023u;
            bool f0 = ty0 < unrel, f1 = ty1 < unrel, f2 = ty2 < unrel, f3 = ty3 < unrel;
            float dc0 = dinvAll[(f0 ? 0 : nent) + p0.x];
            float dc1 = dinvAll[(f1 ? 0 : nent) + p1.x];
            float dc2 = dinvAll[(f2 ? 0 : nent) + p2.x];
            float dc3 = dinvAll[(f3 ? 0 : nent) + p3.x];
            uint2 t0 = T2[(size_t)ty0 * 32 + l32];
            uint2 t1 = T2[(size_t)ty1 * 32 + l32];
            uint2 t2 = T2[(size_t)ty2 * 32 + l32];
            uint2 t3 = T2[(size_t)ty3 * 32 + l32];
            float c0 = 0.5f * (f0 ? da_in : da_out) * dc0;
            float c1 = 0.5f * (f1 ? da_in : da_out) * dc1;
            float c2 = 0.5f * (f2 ? da_in : da_out) * dc2;
            float c3 = 0.5f * (f3 ? da_in : da_out) * dc3;
            FMA4(a, c0, t0) FMA4(a, c1, t1) FMA4(a, c2, t2) FMA4(a, c3, t3)
        }
        for (; i < s1; ++i) {
            uint2 p = sp[i];
            unsigned ty = p.y & 1023u;
            bool f = ty < unrel;
            float c = 0.5f * (f ? da_in : da_out) * dinvAll[(f ? 0 : nent) + p.x];
            uint2 t = T2[(size_t)ty * 32 + l32];
            FMA4(a, c, t)
        }
        // overflow tail (n > CAP): correctness fallback
        for (unsigned j = start + (unsigned)nin; j < end; ++j) {
            uint2 p = payload[j];
            if (((p.y >> 10) & 127u) == (unsigned)r) {
                unsigned ty = p.y & 1023u;
                bool f = ty < unrel;
                float c = 0.5f * (f ? da_in : da_out) * dinvAll[(f ? 0 : nent) + p.x];
                uint2 t = T2[(size_t)ty * 32 + l32];
                FMA4(a, c, t)
            }
        }
        if (row < nent) {
            if (use_bf) {
                hb2[(size_t)row * 32 + l32] = make_uint2(
                    f2bf_rne(a.x) | (f2bf_rne(a.y) << 16),
                    f2bf_rne(a.z) | (f2bf_rne(a.w) << 16));
            } else {
                out4[(size_t)row * 32 + l32] = a;
            }
            s4.x += a.x; s4.y += a.y; s4.z += a.z; s4.w += a.w;
            q4.x += a.x * a.x; q4.y += a.y * a.y; q4.z += a.z * a.z; q4.w += a.w * a.w;
        }
    }
    atomicAdd(&ls[4 * l32 + 0], s4.x); atomicAdd(&ls[4 * l32 + 1], s4.y);
    atomicAdd(&ls[4 * l32 + 2], s4.z); atomicAdd(&ls[4 * l32 + 3], s4.w);
    atomicAdd(&lq[4 * l32 + 0], q4.x); atomicAdd(&lq[4 * l32 + 1], q4.y);
    atomicAdd(&lq[4 * l32 + 2], q4.z); atomicAdd(&lq[4 * l32 + 3], q4.w);
    __syncthreads();
    if (tid < D) {
        atomicAdd(&sums[tid], ls[tid]);
        atomicAdd(&sumsq[tid], lq[tid]);
    }
}

// ---------------- BN apply with fused coefficient computation ----------------
__global__ __launch_bounds__(256) void bn_apply2_bf_kernel(
        const unsigned short* __restrict__ h_bf, float* __restrict__ out,
        const float* __restrict__ sums, const float* __restrict__ sumsq,
        const float* __restrict__ gamma, const float* __restrict__ beta,
        const float* __restrict__ rel_embed, float* __restrict__ pass, int nent, int npass4) {
    __shared__ float s_sc[D], s_sh[D];
    if (threadIdx.x < D) {
        int c = threadIdx.x;
        float inv_n = 1.0f / (float)nent;
        float mean = sums[c] * inv_n;
        float var = sumsq[c] * inv_n - mean * mean;
        float istd = rsqrtf(var + 1e-5f);
        float sc = istd * gamma[c];
        s_sc[c] = sc;
        s_sh[c] = beta[c] - mean * sc;
    }
    __syncthreads();
    long total = (long)nent * 32;   // uint2 units (4 elems each)
    long stride = (long)gridDim.x * blockDim.x;
    long idx0 = (long)blockIdx.x * blockDim.x + threadIdx.x;
    const uint2* hb2 = (const uint2*)h_bf;
    float4* out4 = (float4*)out;
    for (long i = idx0; i < total; i += stride) {
        int c0 = (int)((i & 31) << 2);
        uint2 v = hb2[i];
        float4 o;
        o.x = tanhf(__uint_as_float(v.x << 16)         * s_sc[c0 + 0] + s_sh[c0 + 0]);
        o.y = tanhf(__uint_as_float(v.x & 0xffff0000u) * s_sc[c0 + 1] + s_sh[c0 + 1]);
        o.z = tanhf(__uint_as_float(v.y << 16)         * s_sc[c0 + 2] + s_sh[c0 + 2]);
        o.w = tanhf(__uint_as_float(v.y & 0xffff0000u) * s_sc[c0 + 3] + s_sh[c0 + 3]);
        out4[i] = o;
    }
    const float4* re4 = (const float4*)rel_embed;
    float4* p4 = (float4*)pass;
    for (long i = idx0; i < npass4; i += stride) p4[i] = re4[i];
}

// f32 variant (when ws can't hold h_bf)
__global__ __launch_bounds__(256) void bn_apply2_kernel(
        float* __restrict__ h,
        const float* __restrict__ sums, const float* __restrict__ sumsq,
        const float* __restrict__ gamma, const float* __restrict__ beta,
        const float* __restrict__ rel_embed, float* __restrict__ pass, int nent, int npass4) {
    __shared__ float s_sc[D], s_sh[D];
    if (threadIdx.x < D) {
        int c = threadIdx.x;
        float inv_n = 1.0f / (float)nent;
        float mean = sums[c] * inv_n;
        float var = sumsq[c] * inv_n - mean * mean;
        float istd = rsqrtf(var + 1e-5f);
        float sc = istd * gamma[c];
        s_sc[c] = sc;
        s_sh[c] = beta[c] - mean * sc;
    }
    __syncthreads();
    long total = (long)nent * (D / 4);
    long stride = (long)gridDim.x * blockDim.x;
    long idx0 = (long)blockIdx.x * blockDim.x + threadIdx.x;
    float4* h4 = (float4*)h;
    for (long i = idx0; i < total; i += stride) {
        int c0 = (int)((i & 31) << 2);
        float4 v = h4[i];
        v.x = tanhf(v.x * s_sc[c0 + 0] + s_sh[c0 + 0]);
        v.y = tanhf(v.y * s_sc[c0 + 1] + s_sh[c0 + 1]);
        v.z = tanhf(v.z * s_sc[c0 + 2] + s_sh[c0 + 2]);
        v.w = tanhf(v.w * s_sc[c0 + 3] + s_sh[c0 + 3]);
        h4[i] = v;
    }
    const float4* re4 = (const float4*)rel_embed;
    float4* p4 = (float4*)pass;
    for (long i = idx0; i < npass4; i += stride) p4[i] = re4[i];
}

// ---------------- fallback (atomic) path kernels ----------------
__global__ __launch_bounds__(256) void degree_kernel(const int* __restrict__ rows, int E,
                                                     float* __restrict__ deg_in,
                                                     float* __restrict__ deg_out) {
    int total = 2 * E;
    int tid = blockIdx.x * blockDim.x + threadIdx.x;
    int nth = gridDim.x * blockDim.x;
    for (long b = (long)tid * BUNROLL; b < total; b += (long)nth * BUNROLL) {
        for (int k = 0; k < BUNROLL && b + k < total; ++k) {
            int r = rows[b + k];
            float* deg = (b + k < E) ? deg_in : deg_out;
            atomicAdd(&deg[r], 1.0f);
        }
    }
}

__global__ void scatter_kernel(const int* __restrict__ rows, const int* __restrict__ cols,
                               const int* __restrict__ etype,
                               const float* __restrict__ deg_in, const float* __restrict__ deg_out,
                               const float* __restrict__ T_in, const float* __restrict__ T_out,
                               float* __restrict__ out, int E) {
    int wave = (blockIdx.x * blockDim.x + threadIdx.x) >> 6;
    int lane = threadIdx.x & 63;
    int nwaves = (gridDim.x * blockDim.x) >> 6;
    int total = 2 * E;
    for (int e = wave; e < total; e += nwaves) {
        bool first = (e < E);
        int row = rows[e];
        int col = cols[e];
        int t = etype[e];
        const float* deg = first ? deg_in : deg_out;
        const float* T = first ? T_in : T_out;
        float dr = deg[row];
        float dc = deg[col];
        float norm = (dr > 0.f ? rsqrtf(dr) : 0.f) * (dc > 0.f ? rsqrtf(dc) : 0.f);
        float c = 0.5f * norm;
        if (c != 0.f) {
            float v0 = c * T[t * D + lane];
            float v1 = c * T[t * D + 64 + lane];
            long b = (long)row * D;
            atomicAdd(&out[b + lane], v0);
            atomicAdd(&out[b + 64 + lane], v1);
        }
    }
}

__global__ void bn_stats_kernel(const float* __restrict__ h, int nent,
                                float* __restrict__ sums, float* __restrict__ sumsq) {
    int col = threadIdx.x;
    float s = 0.f, s2 = 0.f;
    for (int r = blockIdx.x; r < nent; r += gridDim.x) {
        float v = h[(long)r * D + col];
        s += v;
        s2 += v * v;
    }
    atomicAdd(&sums[col], s);
    atomicAdd(&sumsq[col], s2);
}

__global__ void bn_apply_kernel(float* __restrict__ h,
                                const float* __restrict__ sums, const float* __restrict__ sumsq,
                                const float* __restrict__ gamma, const float* __restrict__ beta,
                                int nent) {
    long total = ((long)nent * D) / 4;
    long stride = (long)gridDim.x * blockDim.x;
    float inv_n = 1.0f / (float)nent;
    float4* h4 = (float4*)h;
    for (long i = (long)blockIdx.x * blockDim.x + threadIdx.x; i < total; i += stride) {
        int c0 = (int)((i * 4) & (D - 1));
        float4 v = h4[i];
        float r[4] = {v.x, v.y, v.z, v.w};
#pragma unroll
        for (int j = 0; j < 4; ++j) {
            int col = c0 + j;
            float mean = sums[col] * inv_n;
            float var = sumsq[col] * inv_n - mean * mean;
            float istd = rsqrtf(var + 1e-5f);
            r[j] = tanhf((r[j] - mean) * istd * gamma[col] + beta[col]);
        }
        h4[i] = make_float4(r[0], r[1], r[2], r[3]);
    }
}

extern "C" void kernel_launch(void* const* d_in, const int* in_sizes, int n_in,
                              void* d_out, int out_size, void* d_ws, size_t ws_size,
                              hipStream_t stream) {
    const float* rel_embed     = (const float*)d_in[0];
    const float* rel_embed_in  = (const float*)d_in[1];
    const float* rel_embed_out = (const float*)d_in[2];
    const float* w_in          = (const float*)d_in[3];
    const float* w_out         = (const float*)d_in[4];
    const float* bn_gamma      = (const float*)d_in[5];
    const float* bn_beta       = (const float*)d_in[6];
    const int*   edge_index    = (const int*)d_in[7];
    const int*   edge_type     = (const int*)d_in[8];

    const int nrel = in_sizes[0] / D;               // 500
    const int E2   = in_sizes[8];                   // 3,000,000
    const int E    = E2 / 2;                        // 1,500,000
    const int nent = (out_size - in_sizes[0]) / D;  // 200,000
    const int K    = (nent + RPB - 1) / RPB;        // 1563 buckets
    const int NB   = (E2 + CHUNK4 - 1) / CHUNK4;    // 184 blocks
    const long NBK = (long)NB * K;                  // ~288K counters
    const int ntiles = (int)((NBK + STILE - 1) / STILE);  // ~281
    const int NT4  = (2 * nrel + 3) / 4;            // 250 transform blocks

    float* out = (float*)d_out;
    const int* rows = edge_index;
    const int* cols = edge_index + E2;

    // ---- workspace layout (fast path) ----
    float*          ws       = (float*)d_ws;
    float*          dinvAll  = ws;                                   // 2*nent
    float*          sums     = dinvAll + (size_t)2 * nent;           // D
    float*          sumsq    = sums + D;                             // D
    unsigned*       rowBase  = (unsigned*)(sumsq + D);               // K*RPB
    unsigned*       cnt      = rowBase + (size_t)K * RPB;            // NBK+1 (scan in place)
    unsigned*       tsum     = cnt + NBK + 1;                        // ntiles
    unsigned*       toff     = tsum + ntiles;                        // ntiles
    unsigned short* T_bf     = (unsigned short*)(toff + ntiles);     // 2*nrel*D bf16
    uintptr_t pal = ((uintptr_t)(T_bf + (size_t)2 * nrel * D) + 15) & ~(uintptr_t)15;
    uint2*          payload  = (uint2*)pal;                          // E2
    uintptr_t pal2 = ((uintptr_t)(payload + E2) + 15) & ~(uintptr_t)15;
    unsigned short* h_bf     = (unsigned short*)pal2;                // nent*D bf16 (optional)
    size_t needed    = pal2 - (uintptr_t)d_ws;
    size_t needed_bf = needed + (size_t)nent * D * sizeof(unsigned short);

    bool fast   = (needed <= ws_size) && (K <= MAXK) && (2 * nrel <= 1024) &&
                  (ntiles <= 1024);
    int  use_bf = fast && (needed_bf <= ws_size);

    if (fast) {
        fused_th_kernel<<<NT4 + NB, 512, 0, stream>>>(rel_embed_in, w_in,
                                                      rel_embed_out, w_out, T_bf, nrel, NT4,
                                                      rows, E2, cnt, NB, K);
        tile_sum_u32<<<ntiles, 256, 0, stream>>>(cnt, tsum, (int)NBK);
        scan_tiles_kernel<<<1, 1024, 0, stream>>>(tsum, toff, cnt, ntiles, (int)NBK);
        base_write_u32<<<ntiles, 256, 0, stream>>>(cnt, toff, cnt, (int)NBK);
        scatter4_kernel<<<NB, 512, 0, stream>>>(rows, cols, edge_type, cnt,
                                                payload, E, E2, nrel, NB, K);
        degsort_kernel<<<K, 512, 0, stream>>>(cnt, payload, dinvAll, rowBase, sums,
                                              nent, nrel, NB, K);
        accum4_kernel<<<K, 512, 0, stream>>>(cnt, payload, T_bf, dinvAll, rowBase,
                                             out, h_bf, use_bf, sums, sumsq,
                                             nent, nrel, NB, K);
        if (use_bf) {
            bn_apply2_bf_kernel<<<2048, 256, 0, stream>>>(h_bf, out, sums, sumsq,
                                                          bn_gamma, bn_beta, rel_embed,
                                                          out + (size_t)nent * D, nent,
                                                          (nrel * D) / 4);
        } else {
            bn_apply2_kernel<<<2048, 256, 0, stream>>>(out, sums, sumsq,
                                                       bn_gamma, bn_beta, rel_embed,
                                                       out + (size_t)nent * D, nent,
                                                       (nrel * D) / 4);
        }
    } else {
        // ---------- fallback atomic path (f32 everywhere) ----------
        float* f_deg_in  = ws;
        float* f_deg_out = f_deg_in + nent;
        float* f_T_in    = f_deg_out + nent;
        float* f_T_out   = f_T_in + (size_t)nrel * D;
        float* f_sums    = f_T_out + (size_t)nrel * D;
        float* f_sumsq   = f_sums + D;

        hipMemsetAsync(out, 0, (size_t)nent * D * sizeof(float), stream);
        hipMemsetAsync(f_deg_in, 0, (size_t)2 * nent * sizeof(float), stream);
        hipMemsetAsync(f_sums, 0, (size_t)2 * D * sizeof(float), stream);

        transform2_kernel<<<2 * nrel, D, 0, stream>>>(rel_embed_in, w_in, rel_embed_out, w_out,
                                                      f_T_in, nrel);
        degree_kernel<<<1466, 256, 0, stream>>>(edge_index, E, f_deg_in, f_deg_out);
        scatter_kernel<<<2048, 256, 0, stream>>>(rows, cols, edge_type, f_deg_in, f_deg_out,
                                                 f_T_in, f_T_out, out, E);
        bn_stats_kernel<<<1024, D, 0, stream>>>(out, nent, f_sums, f_sumsq);
        bn_apply_kernel<<<4096, 256, 0, stream>>>(out, f_sums, f_sumsq, bn_gamma, bn_beta, nent);
        hipMemcpyAsync(out + (size_t)nent * D, rel_embed,
                       (size_t)nrel * D * sizeof(float), hipMemcpyDeviceToDevice, stream);
    }
}